// Round 11
// baseline (2440.443 us; speedup 1.0000x reference)
//
#include <hip/hip_runtime.h>

typedef __attribute__((ext_vector_type(8))) short short8;
typedef __attribute__((ext_vector_type(4))) float f32x4;

#define AS1 __attribute__((address_space(1)))
#define AS3 __attribute__((address_space(3)))

__device__ __forceinline__ unsigned short f2bf(float f) {
  unsigned int u = __float_as_uint(f);
  u = (u + 0x7fffu + ((u >> 16) & 1u)) >> 16;   // RNE
  return (unsigned short)u;
}
__device__ __forceinline__ float bf2f(unsigned short b) {
  return __uint_as_float(((unsigned int)b) << 16);
}

// ---------------- embedding gather ----------------
__global__ __launch_bounds__(256) void embed_k(const int* __restrict__ ids,
                                               const float* __restrict__ emb,
                                               float* __restrict__ h) {
  const int tok = blockIdx.x;
  const int id = ids[tok];
  const float4* s = (const float4*)(emb + (size_t)id * 2048);
  float4* d = (float4*)(h + (size_t)tok * 2048);
  d[threadIdx.x * 2] = s[threadIdx.x * 2];
  d[threadIdx.x * 2 + 1] = s[threadIdx.x * 2 + 1];
}

// ---------------- rope tables ----------------
__global__ __launch_bounds__(256) void ropetab_k(float* __restrict__ ct, float* __restrict__ st) {
  int i = blockIdx.x * 256 + threadIdx.x;  // 32768
  int pos = i >> 6, j = i & 63;
  float inv = __expf(-(float)j * (1.0f / 64.0f) * logf(500000.0f));
  float ang = (float)pos * inv;
  ct[i] = cosf(ang);
  st[i] = sinf(ang);
}

// ---------------- weight conversion fp32 -> bf16 with LoRA-B augmentation ----------------
struct ConvSeg {
  const float* W; const float* Bm; unsigned short* out;
  int N, Kin, Kout, bcol0; long chunk0;
};
struct ConvDesc { long total; int nseg; ConvSeg seg[16]; };

__global__ __launch_bounds__(256) void conv_k(ConvDesc d, float bscale) {
  long c = (long)blockIdx.x * 256 + threadIdx.x;
  if (c >= d.total) return;
  int si = 0;
  while (si + 1 < d.nseg && c >= d.seg[si + 1].chunk0) ++si;
  const float* W = d.seg[si].W;
  const float* Bm = d.seg[si].Bm;
  unsigned short* out = d.seg[si].out;
  const int Kin = d.seg[si].Kin, Kout = d.seg[si].Kout, bcol0 = d.seg[si].bcol0;
  long lc = c - d.seg[si].chunk0;
  int cpr = Kout >> 3;
  int row = (int)(lc / cpr);
  int col0 = ((int)(lc - (long)row * cpr)) << 3;
  union { unsigned short u[8]; uint4 v; } o;
  if (col0 < Kin) {
    const float4* src = (const float4*)(W + (size_t)row * Kin + col0);
    float4 a = src[0], b = src[1];
    o.u[0]=f2bf(a.x); o.u[1]=f2bf(a.y); o.u[2]=f2bf(a.z); o.u[3]=f2bf(a.w);
    o.u[4]=f2bf(b.x); o.u[5]=f2bf(b.y); o.u[6]=f2bf(b.z); o.u[7]=f2bf(b.w);
  } else {
    #pragma unroll
    for (int j = 0; j < 8; ++j) {
      int bj = col0 + j - bcol0;
      float v = (Bm && bj >= 0 && bj < 64) ? Bm[(size_t)row * 64 + bj] * bscale : 0.0f;
      o.u[j] = f2bf(v);
    }
  }
  *(uint4*)(out + (size_t)row * Kout + col0) = o.v;
}

// ---------------- RMSNorm (D=2048) -> bf16 row at stride ldx ----------------
__global__ __launch_bounds__(256) void rms_bf16_k(const float* __restrict__ h,
                                                  const float* __restrict__ w,
                                                  unsigned short* __restrict__ out, int ldx) {
  const int tok = blockIdx.x, t = threadIdx.x;
  const float4* row = (const float4*)(h + (size_t)tok * 2048);
  float4 v0 = row[t * 2], v1 = row[t * 2 + 1];
  float ss = v0.x*v0.x+v0.y*v0.y+v0.z*v0.z+v0.w*v0.w
           + v1.x*v1.x+v1.y*v1.y+v1.z*v1.z+v1.w*v1.w;
  #pragma unroll
  for (int x = 32; x > 0; x >>= 1) ss += __shfl_xor(ss, x, 64);
  __shared__ float sred[4];
  if ((t & 63) == 0) sred[t >> 6] = ss;
  __syncthreads();
  ss = sred[0] + sred[1] + sred[2] + sred[3];
  const float sc = rsqrtf(ss * (1.0f / 2048.0f) + 1e-5f);
  const int d0 = t * 8;
  const float vals[8] = {v0.x, v0.y, v0.z, v0.w, v1.x, v1.y, v1.z, v1.w};
  union { unsigned short u[8]; uint4 v; } o;
  #pragma unroll
  for (int j = 0; j < 8; ++j) o.u[j] = f2bf(vals[j] * sc * w[d0 + j]);
  *(uint4*)(out + (size_t)tok * ldx + d0) = o.v;
}

// ---------------- final RMSNorm -> fp32 ----------------
__global__ __launch_bounds__(256) void rms_f32_k(const float* __restrict__ h,
                                                 const float* __restrict__ w,
                                                 float* __restrict__ out) {
  const int tok = blockIdx.x, t = threadIdx.x;
  const float4* row = (const float4*)(h + (size_t)tok * 2048);
  float4 v0 = row[t * 2], v1 = row[t * 2 + 1];
  float ss = v0.x*v0.x+v0.y*v0.y+v0.z*v0.z+v0.w*v0.w
           + v1.x*v1.x+v1.y*v1.y+v1.z*v1.z+v1.w*v1.w;
  #pragma unroll
  for (int x = 32; x > 0; x >>= 1) ss += __shfl_xor(ss, x, 64);
  __shared__ float sred[4];
  if ((t & 63) == 0) sred[t >> 6] = ss;
  __syncthreads();
  ss = sred[0] + sred[1] + sred[2] + sred[3];
  const float sc = rsqrtf(ss * (1.0f / 2048.0f) + 1e-5f);
  const int d0 = t * 8;
  float4 o0, o1;
  o0.x = v0.x * sc * w[d0 + 0]; o0.y = v0.y * sc * w[d0 + 1];
  o0.z = v0.z * sc * w[d0 + 2]; o0.w = v0.w * sc * w[d0 + 3];
  o1.x = v1.x * sc * w[d0 + 4]; o1.y = v1.y * sc * w[d0 + 5];
  o1.z = v1.z * sc * w[d0 + 6]; o1.w = v1.w * sc * w[d0 + 7];
  float4* op = (float4*)(out + (size_t)tok * 2048 + d0);
  op[0] = o0; op[1] = o1;
}

// ---------------- split-K LoRA GEMM: f32 partial slabs (no atomics) ----------------
__global__ __launch_bounds__(256) void gemm_sk_k(
    const unsigned short* __restrict__ A, int lda,
    const unsigned short* __restrict__ B, int ldb, int Nb, int KS,
    float* __restrict__ Cf, long slabStride, int ldc) {
  __shared__ unsigned short As[128 * 64];
  __shared__ unsigned short Bs[128 * 64];
  const int t = threadIdx.x;
  const int w = t >> 6, l = t & 63;
  const int lr = l & 15, lg = l >> 4;
  const int m0 = blockIdx.x * 128;
  const int n0 = blockIdx.y * 128;
  const int wr = (w >> 1) * 64, wc = (w & 1) * 64;
  const int koff = blockIdx.z * KS;

  const f32x4 vzero = {0.f, 0.f, 0.f, 0.f};
  f32x4 acc[4][4];
  #pragma unroll
  for (int i = 0; i < 4; ++i)
    #pragma unroll
    for (int j = 0; j < 4; ++j) acc[i][j] = vzero;

  const int scol = ((t & 7) ^ ((t >> 3) & 7)) * 8;
  const unsigned short* aSrc = A + (size_t)(m0 + (t >> 3)) * lda + koff + scol;
  const int bRow0 = n0 + (t >> 3);

  for (int k0 = 0; k0 < KS; k0 += 64) {
    __syncthreads();
    #pragma unroll
    for (int i = 0; i < 4; ++i) {
      __builtin_amdgcn_global_load_lds((const AS1 void*)(aSrc + (size_t)i * 32 * lda + k0),
                                       (AS3 void*)(As + i * 2048 + w * 512), 16, 0, 0);
      int br = bRow0 + i * 32; br = br < Nb ? br : Nb - 1;
      __builtin_amdgcn_global_load_lds((const AS1 void*)(B + (size_t)br * ldb + koff + k0 + scol),
                                       (AS3 void*)(Bs + i * 2048 + w * 512), 16, 0, 0);
    }
    __syncthreads();
    #pragma unroll
    for (int kk = 0; kk < 64; kk += 32) {
      const int swz = ((lg + (kk >> 3)) ^ (lr & 7)) << 3;
      short8 af[4], bfr[4];
      #pragma unroll
      for (int i = 0; i < 4; ++i)
        af[i] = *(const short8*)&As[(wr + i * 16 + lr) * 64 + swz];
      #pragma unroll
      for (int j = 0; j < 4; ++j)
        bfr[j] = *(const short8*)&Bs[(wc + j * 16 + lr) * 64 + swz];
      #pragma unroll
      for (int i = 0; i < 4; ++i)
        #pragma unroll
        for (int j = 0; j < 4; ++j)
          acc[i][j] = __builtin_amdgcn_mfma_f32_16x16x32_bf16(af[i], bfr[j], acc[i][j], 0, 0, 0);
    }
  }

  float* slab = Cf + (size_t)blockIdx.z * slabStride;
  #pragma unroll
  for (int i = 0; i < 4; ++i) {
    const int row = m0 + wr + i * 16 + lg * 4;
    #pragma unroll
    for (int j = 0; j < 4; ++j) {
      const int col = n0 + wc + j * 16 + lr;
      if (col < Nb) {
        #pragma unroll
        for (int r = 0; r < 4; ++r)
          slab[(size_t)(row + r) * ldc + col] = acc[i][j][r];
      }
    }
  }
}

// ---------------- sum split-K slabs -> bf16 tail columns ----------------
__global__ __launch_bounds__(256) void cvt_tail_k(const float* __restrict__ slab,
                                                  long slabStride, int S, int N,
                                                  unsigned short* __restrict__ out,
                                                  int ldx, int col0) {
  int i = blockIdx.x * 256 + threadIdx.x;
  if (i >= 4096 * N) return;
  int row = i / N, col = i - row * N;
  float s = 0.f;
  for (int z = 0; z < S; ++z) s += slab[(size_t)z * slabStride + (size_t)row * N + col];
  out[(size_t)row * ldx + col0 + col] = f2bf(s);
}

// ---------------- big GEMM: 256x256, K-half ring, counted vmcnt ----------------
// SINGLE template instantiation <2240,2240,2240> (compile-time K -> full unroll; exactly
// one 8p instantiation in module -- the r8-fast configuration). qkv native K=2240;
// gate/up K-padded to 2240 via zero weight-tail columns (exact). epi is a RUNTIME arg
// (uniform end-of-kernel branch) so all three call sites share one symbol.
// epi 0: Cb=bf16(acc); 1: Cf+=acc; 2: Cb=bf16(silu(G)*acc).
template<int K_, int LDA_, int LDB_>
__global__ __launch_bounds__(512, 2) void gemm8p_k(
    const unsigned short* __restrict__ A,
    const unsigned short* __restrict__ B,
    unsigned short* __restrict__ Cb, float* __restrict__ Cf, int ldc, int epi,
    const unsigned short* __restrict__ G, int ldg) {
  __shared__ __attribute__((aligned(16))) unsigned short As[4][256 * 32];
  __shared__ __attribute__((aligned(16))) unsigned short Bs[4][256 * 32];
  const int t = threadIdx.x;
  const int w = t >> 6, l = t & 63;
  const int lr = l & 15, lg = l >> 4;

  const int gy = gridDim.y;
  int flat = blockIdx.x + gridDim.x * blockIdx.y;
  const int cpx = (gridDim.x * gy) >> 3;
  flat = (flat & 7) * cpx + (flat >> 3);
  const int m0 = (flat / gy) * 256;
  const int n0 = (flat % gy) * 256;

  const int wr = (w >> 2) * 128;
  const int wc = (w & 3) * 64;

  const f32x4 vzero = {0.f, 0.f, 0.f, 0.f};
  f32x4 acc[8][4];
  #pragma unroll
  for (int i = 0; i < 8; ++i)
    #pragma unroll
    for (int j = 0; j < 4; ++j) acc[i][j] = vzero;

  const int x = (l & 7) ^ (l >> 3);
  const int srow = w * 32 + 2 * (l >> 3) + (x >> 2);
  const int scol = (x & 3) * 8;
  const unsigned short* aS0 = A + (size_t)(m0 + srow) * LDA_ + scol;
  const unsigned short* aS1 = aS0 + (size_t)16 * LDA_;
  const unsigned short* bS0 = B + (size_t)(n0 + srow) * LDB_ + scol;
  const unsigned short* bS1 = bS0 + (size_t)16 * LDB_;
  char* AsD = (char*)&As[0][0] + w * 2048;
  char* BsD = (char*)&Bs[0][0] + w * 2048;

  auto stA = [&](int slot, int kb) {
    __builtin_amdgcn_global_load_lds((const AS1 void*)(aS0 + kb),
                                     (AS3 void*)(AsD + slot * 16384), 16, 0, 0);
    __builtin_amdgcn_global_load_lds((const AS1 void*)(aS1 + kb),
                                     (AS3 void*)(AsD + slot * 16384 + 1024), 16, 0, 0);
  };
  auto stB = [&](int slot, int kb) {
    __builtin_amdgcn_global_load_lds((const AS1 void*)(bS0 + kb),
                                     (AS3 void*)(BsD + slot * 16384), 16, 0, 0);
    __builtin_amdgcn_global_load_lds((const AS1 void*)(bS1 + kb),
                                     (AS3 void*)(BsD + slot * 16384 + 1024), 16, 0, 0);
  };

  const int rdoff = (lr >> 1) * 128 + (((lg | ((lr & 1) << 2)) ^ (lr >> 1)) << 4);
  #define RD(arr, slot, Rb) \
    (*(const short8*)((const char*)(arr) + (slot) * 16384 + (Rb) * 64 + rdoff))

  stA(0, 0); stB(0, 0);
  stA(1, 32); stB(1, 32);
  asm volatile("s_waitcnt vmcnt(4)" ::: "memory");
  __builtin_amdgcn_s_barrier();

  constexpr int NT = K_ / 64;
  short8 a0[4], a1[4], b0[4], b1[4];

  for (int tt = 0; tt < NT; ++tt) {
    const int g0 = 2 * tt;
    const int s0 = g0 & 3, s1 = (g0 + 1) & 3, vA = (g0 + 2) & 3, vB = (g0 + 3) & 3;
    const bool pf = (tt + 1 < NT);
    const int kbN = pf ? (tt + 1) * 64 : 0;

    // ---- P0 ----
    #pragma unroll
    for (int i = 0; i < 4; ++i) a0[i] = RD(As, s0, wr + i * 16);
    #pragma unroll
    for (int j = 0; j < 4; ++j) b0[j] = RD(Bs, s0, wc + j * 16);
    if (pf) stA(vA, kbN);
    __builtin_amdgcn_s_barrier();
    __builtin_amdgcn_s_setprio(1);
    #pragma unroll
    for (int i = 0; i < 4; ++i)
      #pragma unroll
      for (int j = 0; j < 4; ++j)
        acc[i][j] = __builtin_amdgcn_mfma_f32_16x16x32_bf16(a0[i], b0[j], acc[i][j], 0, 0, 0);
    __builtin_amdgcn_s_setprio(0);
    __builtin_amdgcn_s_barrier();

    // ---- P1 ----
    #pragma unroll
    for (int i = 0; i < 4; ++i) a1[i] = RD(As, s0, wr + 64 + i * 16);
    if (pf) {
      stB(vA, kbN);
      asm volatile("s_waitcnt vmcnt(4)" ::: "memory");
    } else {
      asm volatile("s_waitcnt vmcnt(0)" ::: "memory");
    }
    __builtin_amdgcn_s_barrier();
    __builtin_amdgcn_s_setprio(1);
    #pragma unroll
    for (int i = 0; i < 4; ++i)
      #pragma unroll
      for (int j = 0; j < 4; ++j)
        acc[i + 4][j] = __builtin_amdgcn_mfma_f32_16x16x32_bf16(a1[i], b0[j], acc[i + 4][j], 0, 0, 0);
    __builtin_amdgcn_s_setprio(0);
    __builtin_amdgcn_s_barrier();

    // ---- P2 ----
    #pragma unroll
    for (int i = 0; i < 4; ++i) a0[i] = RD(As, s1, wr + i * 16);
    #pragma unroll
    for (int j = 0; j < 4; ++j) b1[j] = RD(Bs, s1, wc + j * 16);
    if (pf) stA(vB, kbN + 32);
    __builtin_amdgcn_s_barrier();
    __builtin_amdgcn_s_setprio(1);
    #pragma unroll
    for (int i = 0; i < 4; ++i)
      #pragma unroll
      for (int j = 0; j < 4; ++j)
        acc[i][j] = __builtin_amdgcn_mfma_f32_16x16x32_bf16(a0[i], b1[j], acc[i][j], 0, 0, 0);
    __builtin_amdgcn_s_setprio(0);
    __builtin_amdgcn_s_barrier();

    // ---- P3 ----
    #pragma unroll
    for (int i = 0; i < 4; ++i) a1[i] = RD(As, s1, wr + 64 + i * 16);
    if (pf) {
      stB(vB, kbN + 32);
      asm volatile("s_waitcnt vmcnt(4)" ::: "memory");
    } else {
      asm volatile("s_waitcnt vmcnt(0)" ::: "memory");
    }
    __builtin_amdgcn_s_barrier();
    __builtin_amdgcn_s_setprio(1);
    #pragma unroll
    for (int i = 0; i < 4; ++i)
      #pragma unroll
      for (int j = 0; j < 4; ++j)
        acc[i + 4][j] = __builtin_amdgcn_mfma_f32_16x16x32_bf16(a1[i], b1[j], acc[i + 4][j], 0, 0, 0);
    __builtin_amdgcn_s_setprio(0);
    __builtin_amdgcn_s_barrier();
  }
  #undef RD

  #pragma unroll
  for (int i = 0; i < 8; ++i) {
    const int row = m0 + wr + i * 16 + lg * 4;
    #pragma unroll
    for (int j = 0; j < 4; ++j) {
      const int col = n0 + wc + j * 16 + lr;
      #pragma unroll
      for (int r = 0; r < 4; ++r) {
        float v = acc[i][j][r];
        size_t off = (size_t)(row + r) * ldc + col;
        if (epi == 0) {
          Cb[off] = f2bf(v);
        } else if (epi == 1) {
          Cf[off] += v;
        } else {
          float g = bf2f(G[(size_t)(row + r) * ldg + col]);
          Cb[off] = f2bf(g / (1.0f + __expf(-g)) * v);
        }
      }
    }
  }
}

// ---------------- 2p GEMM (small-N shapes, 512-block grids): 128x128, dbuf, swizzle ----------------
template<int K_, int LDA_, int LDB_, int EPI_>
__global__ __launch_bounds__(256) void gemm2p_k(
    const unsigned short* __restrict__ A,
    const unsigned short* __restrict__ B,
    unsigned short* __restrict__ Cb, float* __restrict__ Cf, int ldc,
    const unsigned short* __restrict__ G, int ldg) {
  __shared__ unsigned short As[2][128 * 64];
  __shared__ unsigned short Bs[2][128 * 64];
  const int t = threadIdx.x;
  const int w = t >> 6, l = t & 63;
  const int lr = l & 15, lg = l >> 4;

  const int gx = gridDim.x;
  int flat = blockIdx.x + gx * blockIdx.y;
  const int cpx = (gx * gridDim.y) >> 3;
  flat = (flat & 7) * cpx + (flat >> 3);
  const int m0 = (flat % gx) * 128;
  const int n0 = (flat / gx) * 128;

  const int wr = (w >> 1) * 64, wc = (w & 1) * 64;

  const f32x4 vzero = {0.f, 0.f, 0.f, 0.f};
  f32x4 acc[4][4];
  #pragma unroll
  for (int i = 0; i < 4; ++i)
    #pragma unroll
    for (int j = 0; j < 4; ++j) acc[i][j] = vzero;

  const int scol = ((t & 7) ^ ((t >> 3) & 7)) * 8;
  const unsigned short* aSrc = A + (size_t)(m0 + (t >> 3)) * LDA_ + scol;
  const unsigned short* bSrc = B + (size_t)(n0 + (t >> 3)) * LDB_ + scol;

  auto stage = [&](int buf, int k0) {
    #pragma unroll
    for (int i = 0; i < 4; ++i) {
      __builtin_amdgcn_global_load_lds((const AS1 void*)(aSrc + (size_t)i * 32 * LDA_ + k0),
                                       (AS3 void*)(&As[buf][i * 2048 + w * 512]), 16, 0, 0);
      __builtin_amdgcn_global_load_lds((const AS1 void*)(bSrc + (size_t)i * 32 * LDB_ + k0),
                                       (AS3 void*)(&Bs[buf][i * 2048 + w * 512]), 16, 0, 0);
    }
  };

  constexpr int NT = K_ / 64;
  stage(0, 0);
  __syncthreads();

  int cur = 0;
  for (int kt = 0; kt < NT; ++kt) {
    if (kt + 1 < NT) stage(cur ^ 1, (kt + 1) * 64);
    #pragma unroll
    for (int kk = 0; kk < 64; kk += 32) {
      const int swz = ((lg + (kk >> 3)) ^ (lr & 7)) << 3;
      short8 af[4], bfr[4];
      #pragma unroll
      for (int i = 0; i < 4; ++i)
        af[i] = *(const short8*)&As[cur][(wr + i * 16 + lr) * 64 + swz];
      #pragma unroll
      for (int j = 0; j < 4; ++j)
        bfr[j] = *(const short8*)&Bs[cur][(wc + j * 16 + lr) * 64 + swz];
      #pragma unroll
      for (int i = 0; i < 4; ++i)
        #pragma unroll
        for (int j = 0; j < 4; ++j)
          acc[i][j] = __builtin_amdgcn_mfma_f32_16x16x32_bf16(af[i], bfr[j], acc[i][j], 0, 0, 0);
    }
    __syncthreads();
    cur ^= 1;
  }

  #pragma unroll
  for (int i = 0; i < 4; ++i) {
    const int row = m0 + wr + i * 16 + lg * 4;
    #pragma unroll
    for (int j = 0; j < 4; ++j) {
      const int col = n0 + wc + j * 16 + lr;
      #pragma unroll
      for (int r = 0; r < 4; ++r) {
        float v = acc[i][j][r];
        size_t off = (size_t)(row + r) * ldc + col;
        if constexpr (EPI_ == 0) {
          Cb[off] = f2bf(v);
        } else if constexpr (EPI_ == 1) {
          Cf[off] += v;
        } else {
          float g = bf2f(G[(size_t)(row + r) * ldg + col]);
          Cb[off] = f2bf(g / (1.0f + __expf(-g)) * v);
        }
      }
    }
  }
}

// ---------------- RoPE in-place on qkv buffer ----------------
__global__ __launch_bounds__(256) void rope_k(unsigned short* __restrict__ qkv,
                                              const float* __restrict__ ct,
                                              const float* __restrict__ st) {
  const int tok = blockIdx.x;
  const int pid = blockIdx.y * 256 + threadIdx.x;  // 0..1535
  const int head = pid >> 6, j = pid & 63;
  const int s = tok & 511;
  unsigned short* base = qkv + (size_t)tok * 4096 + (head < 16 ? head * 128 : 2048 + (head - 16) * 128);
  const float c = ct[s * 64 + j], sn = st[s * 64 + j];
  const float x1 = bf2f(base[j]), x2 = bf2f(base[j + 64]);
  base[j] = f2bf(x1 * c - x2 * sn);
  base[j + 64] = f2bf(x2 * c + x1 * sn);
}

// ---------------- flash attention ----------------
__global__ __launch_bounds__(256) void attn_k(const unsigned short* __restrict__ qkv,
                                              const int* __restrict__ amask,
                                              unsigned short* __restrict__ xo) {
  const int q0 = blockIdx.x * 64;
  const int hh = blockIdx.y;
  const int b = blockIdx.z;
  const int kvh = hh >> 1;
  const int t = threadIdx.x, w = t >> 6, l = t & 63;
  const int lr = l & 15, lg = l >> 4;

  const size_t rowbase = (size_t)b * 512 * 4096;
  const unsigned short* Q = qkv + rowbase + hh * 128;
  const unsigned short* Kp = qkv + rowbase + 2048 + kvh * 128;
  const unsigned short* Vp = qkv + rowbase + 3072 + kvh * 128;

  __shared__ unsigned short Ks[32 * 128];
  __shared__ unsigned short Vt[128 * 32];
  __shared__ unsigned short Ps[4][16 * 32];

  short8 qf[4];
  const unsigned short* qrow = Q + (size_t)(q0 + w * 16 + lr) * 4096;
  #pragma unroll
  for (int kk = 0; kk < 4; ++kk) qf[kk] = *(const short8*)(qrow + kk * 32 + lg * 8);

  const f32x4 vzero = {0.f, 0.f, 0.f, 0.f};
  f32x4 accO[8];
  #pragma unroll
  for (int i = 0; i < 8; ++i) accO[i] = vzero;
  float mrow[4], lrow[4];
  #pragma unroll
  for (int r = 0; r < 4; ++r) { mrow[r] = -1e30f; lrow[r] = 0.f; }

  const int qpos0 = q0 + w * 16 + lg * 4;
  const int ktiles = (q0 + 64) >> 5;
  for (int kt = 0; kt < ktiles; ++kt) {
    const int kbase = kt * 32;
    __syncthreads();
    #pragma unroll
    for (int i = 0; i < 2; ++i) {
      __builtin_amdgcn_global_load_lds(
          (const AS1 void*)(Kp + (size_t)(kbase + i * 16 + (t >> 4)) * 4096 + (t & 15) * 8),
          (AS3 void*)(Ks + i * 2048 + w * 512), 16, 0, 0);
    }
    #pragma unroll
    for (int c = 0; c < 2; ++c) {
      int chunk = c * 256 + t;
      int key = chunk >> 4, ch = chunk & 15;
      short8 v = *(const short8*)(Vp + (size_t)(kbase + key) * 4096 + ch * 8);
      #pragma unroll
      for (int j = 0; j < 8; ++j) Vt[(ch * 8 + j) * 32 + key] = ((const unsigned short*)&v)[j];
    }
    __syncthreads();

    f32x4 sf[2]; sf[0] = vzero; sf[1] = vzero;
    #pragma unroll
    for (int nt = 0; nt < 2; ++nt)
      #pragma unroll
      for (int kk = 0; kk < 4; ++kk) {
        short8 kf = *(const short8*)&Ks[(nt * 16 + lr) * 128 + kk * 32 + lg * 8];
        sf[nt] = __builtin_amdgcn_mfma_f32_16x16x32_bf16(qf[kk], kf, sf[nt], 0, 0, 0);
      }

    float pv[2][4], pmax[4];
    #pragma unroll
    for (int r = 0; r < 4; ++r) pmax[r] = -1e30f;
    #pragma unroll
    for (int nt = 0; nt < 2; ++nt) {
      const int key = kbase + nt * 16 + lr;
      const bool okm = amask[b * 512 + key] != 0;
      #pragma unroll
      for (int r = 0; r < 4; ++r) {
        float s = sf[nt][r] * 0.08838834764831845f;
        if (!okm || key > qpos0 + r) s = -1e9f;
        pv[nt][r] = s;
        pmax[r] = fmaxf(pmax[r], s);
      }
    }
    #pragma unroll
    for (int x = 1; x < 16; x <<= 1)
      #pragma unroll
      for (int r = 0; r < 4; ++r) pmax[r] = fmaxf(pmax[r], __shfl_xor(pmax[r], x, 64));

    float alpha[4];
    #pragma unroll
    for (int r = 0; r < 4; ++r) {
      float mn = fmaxf(mrow[r], pmax[r]);
      alpha[r] = __expf(mrow[r] - mn);
      mrow[r] = mn;
    }
    float rowsum[4];
    #pragma unroll
    for (int r = 0; r < 4; ++r) {
      float p0 = __expf(pv[0][r] - mrow[r]);
      float p1 = __expf(pv[1][r] - mrow[r]);
      pv[0][r] = p0; pv[1][r] = p1;
      rowsum[r] = p0 + p1;
    }
    #pragma unroll
    for (int x = 1; x < 16; x <<= 1)
      #pragma unroll
      for (int r = 0; r < 4; ++r) rowsum[r] += __shfl_xor(rowsum[r], x, 64);
    #pragma unroll
    for (int r = 0; r < 4; ++r) lrow[r] = lrow[r] * alpha[r] + rowsum[r];
    #pragma unroll
    for (int nt = 0; nt < 8; ++nt)
      #pragma unroll
      for (int r = 0; r < 4; ++r) accO[nt][r] *= alpha[r];

    #pragma unroll
    for (int nt = 0; nt < 2; ++nt)
      #pragma unroll
      for (int r = 0; r < 4; ++r)
        Ps[w][(lg * 4 + r) * 32 + nt * 16 + lr] = f2bf(pv[nt][r]);
    __syncthreads();

    short8 pa = *(const short8*)&Ps[w][lr * 32 + lg * 8];
    #pragma unroll
    for (int nt = 0; nt < 8; ++nt) {
      short8 vb = *(const short8*)&Vt[(nt * 16 + lr) * 32 + lg * 8];
      accO[nt] = __builtin_amdgcn_mfma_f32_16x16x32_bf16(pa, vb, accO[nt], 0, 0, 0);
    }
  }

  const size_t tokbase = ((size_t)b * 512 + qpos0) * 2112;
  #pragma unroll
  for (int nt = 0; nt < 8; ++nt) {
    const int col = hh * 128 + nt * 16 + lr;
    #pragma unroll
    for (int r = 0; r < 4; ++r)
      xo[tokbase + (size_t)r * 2112 + col] = f2bf(accO[nt][r] / lrow[r]);
  }
}

// ---------------- masked mean pool ----------------
__global__ __launch_bounds__(256) void pool_k(const float* __restrict__ tmpf,
                                              const int* __restrict__ amask,
                                              float* __restrict__ pooled) {
  const int b = blockIdx.y;
  const int d = blockIdx.x * 256 + threadIdx.x;
  float acc = 0.f, ms = 0.f;
  for (int s = 0; s < 512; ++s) {
    float m = (float)amask[b * 512 + s];
    acc += tmpf[((size_t)b * 512 + s) * 2048 + d] * m;
    ms += m;
  }
  pooled[b * 2048 + d] = acc / fmaxf(ms, 1e-9f);
}

// ---------------- projection ----------------
__global__ __launch_bounds__(256) void proj_k(const float* __restrict__ pooled,
                                              const float* __restrict__ W,
                                              const float* __restrict__ bias,
                                              float* __restrict__ emb) {
  const int idx = blockIdx.x * 4 + (threadIdx.x >> 6);
  const int l = threadIdx.x & 63;
  const int b = idx / 768, pcol = idx - b * 768;
  const float* x = pooled + b * 2048;
  const float* wr = W + (size_t)pcol * 2048;
  float acc = 0.f;
  #pragma unroll
  for (int i = 0; i < 32; ++i) acc += x[l + i * 64] * wr[l + i * 64];
  #pragma unroll
  for (int xm = 32; xm > 0; xm >>= 1) acc += __shfl_xor(acc, xm, 64);
  if (l == 0) emb[b * 768 + pcol] = acc + bias[pcol];
}

// ---------------- L2 normalize ----------------
__global__ __launch_bounds__(256) void norm_k(const float* __restrict__ emb, float* __restrict__ out) {
  const int b = blockIdx.x, t = threadIdx.x;
  float v[3]; float ss = 0.f;
  #pragma unroll
  for (int i = 0; i < 3; ++i) { v[i] = emb[b * 768 + t + i * 256]; ss += v[i] * v[i]; }
  #pragma unroll
  for (int x = 32; x > 0; x >>= 1) ss += __shfl_xor(ss, x, 64);
  __shared__ float sred[4];
  if ((t & 63) == 0) sred[t >> 6] = ss;
  __syncthreads();
  ss = sred[0] + sred[1] + sred[2] + sred[3];
  const float inv = 1.0f / fmaxf(sqrtf(ss), 1e-12f);
  #pragma unroll
  for (int i = 0; i < 3; ++i) out[b * 768 + t + i * 256] = v[i] * inv;
}

extern "C" void kernel_launch(void* const* d_in, const int* in_sizes, int n_in,
                              void* d_out, int out_size, void* d_ws, size_t ws_size,
                              hipStream_t stream) {
  const int* ids = (const int*)d_in[0];
  const int* amask = (const int*)d_in[1];
  const float* tok_emb = (const float*)d_in[2];
  const float* Wq = (const float*)d_in[3];
  const float* Wk = (const float*)d_in[4];
  const float* Wv = (const float*)d_in[5];
  const float* Wo = (const float*)d_in[6];
  const float* Wg = (const float*)d_in[7];
  const float* Wu = (const float*)d_in[8];
  const float* Wd = (const float*)d_in[9];
  const float* Aq = (const float*)d_in[10];
  const float* Bq = (const float*)d_in[11];
  const float* Ak = (const float*)d_in[12];
  const float* Bk = (const float*)d_in[13];
  const float* Av = (const float*)d_in[14];
  const float* Bv = (const float*)d_in[15];
  const float* Ao = (const float*)d_in[16];
  const float* Bo = (const float*)d_in[17];
  const float* Ag = (const float*)d_in[18];
  const float* Bg = (const float*)d_in[19];
  const float* Au = (const float*)d_in[20];
  const float* Bu = (const float*)d_in[21];
  const float* Ad = (const float*)d_in[22];
  const float* Bd = (const float*)d_in[23];
  const float* ln1 = (const float*)d_in[24];
  const float* ln2 = (const float*)d_in[25];
  const float* lnf = (const float*)d_in[26];
  const float* projW = (const float*)d_in[27];
  const float* projb = (const float*)d_in[28];

  typedef unsigned short u16;
  char* p = (char*)d_ws;
  auto take = [&](size_t n) { char* r = p; p += (n + 255) & ~(size_t)255; return r; };
  u16* Wqkv_b = (u16*)take(4096ull * 2240 * 2);
  u16* Wo_b   = (u16*)take(2048ull * 2112 * 2);
  u16* Wg_b   = (u16*)take(8192ull * 2240 * 2);   // K-padded to 2240 (zero tails)
  u16* Wu_b   = (u16*)take(8192ull * 2240 * 2);   // K-padded to 2240 (zero tails)
  u16* Wd_b   = (u16*)take(2048ull * 8256 * 2);
  u16* Aqkv_b = (u16*)take(192ull * 2048 * 2);
  u16* Agu_b  = (u16*)take(128ull * 2048 * 2);
  u16* Ao_b   = (u16*)take(64ull * 2048 * 2);
  u16* Ad_b   = (u16*)take(64ull * 8192 * 2);
  float* hbuf = (float*)take(4096ull * 2048 * 4);
  u16* xq     = (u16*)take(4096ull * 2240 * 2);
  u16* xo     = (u16*)take(4096ull * 2112 * 2);
  u16* xd     = (u16*)take(4096ull * 8256 * 2);
  u16* qkvb   = (u16*)take(4096ull * 4096 * 2);
  u16* gbuf   = (u16*)take(4096ull * 8192 * 2);
  float* ct   = (float*)take(512ull * 64 * 4);
  float* st   = (float*)take(512ull * 64 * 4);
  float* pooled = (float*)take(8ull * 2048 * 4);
  float* embraw = (float*)take(8ull * 768 * 4);
  float* tmpf = (float*)gbuf;
  float* slab = (float*)gbuf;   // split-K partials; stream-ordered reuse of gbuf
  (void)ws_size; (void)in_sizes; (void)n_in; (void)out_size;

  embed_k<<<4096, 256, 0, stream>>>(ids, tok_emb, hbuf);
  ropetab_k<<<128, 256, 0, stream>>>(ct, st);

  for (int l = 0; l < 2; ++l) {
    ConvDesc cd;
    long ch = 0; int si = 0;
    auto seg = [&](const float* W, const float* Bm, u16* out, int N, int Kin, int Kout, int bcol0) {
      cd.seg[si].W = W; cd.seg[si].Bm = Bm; cd.seg[si].out = out;
      cd.seg[si].N = N; cd.seg[si].Kin = Kin; cd.seg[si].Kout = Kout;
      cd.seg[si].bcol0 = bcol0; cd.seg[si].chunk0 = ch;
      ch += (long)N * (Kout >> 3); ++si;
    };
    seg(Wq + (size_t)l * 2048 * 2048, Bq + (size_t)l * 2048 * 64, Wqkv_b,               2048, 2048, 2240, 2048);
    seg(Wk + (size_t)l * 1024 * 2048, Bk + (size_t)l * 1024 * 64, Wqkv_b + 2048ull * 2240, 1024, 2048, 2240, 2112);
    seg(Wv + (size_t)l * 1024 * 2048, Bv + (size_t)l * 1024 * 64, Wqkv_b + 3072ull * 2240, 1024, 2048, 2240, 2176);
    seg(Wo + (size_t)l * 2048 * 2048, Bo + (size_t)l * 2048 * 64, Wo_b, 2048, 2048, 2112, 2048);
    seg(Wg + (size_t)l * 8192 * 2048, Bg + (size_t)l * 8192 * 64, Wg_b, 8192, 2048, 2240, 2048);
    seg(Wu + (size_t)l * 8192 * 2048, Bu + (size_t)l * 8192 * 64, Wu_b, 8192, 2048, 2240, 2112);
    seg(Wd + (size_t)l * 2048 * 8192, Bd + (size_t)l * 2048 * 64, Wd_b, 2048, 8192, 8256, 8192);
    seg(Aq + (size_t)l * 64 * 2048, nullptr, Aqkv_b,                64, 2048, 2048, 1 << 30);
    seg(Ak + (size_t)l * 64 * 2048, nullptr, Aqkv_b + 64ull * 2048, 64, 2048, 2048, 1 << 30);
    seg(Av + (size_t)l * 64 * 2048, nullptr, Aqkv_b + 128ull * 2048, 64, 2048, 2048, 1 << 30);
    seg(Ag + (size_t)l * 64 * 2048, nullptr, Agu_b,                 64, 2048, 2048, 1 << 30);
    seg(Au + (size_t)l * 64 * 2048, nullptr, Agu_b + 64ull * 2048,  64, 2048, 2048, 1 << 30);
    seg(Ao + (size_t)l * 64 * 2048, nullptr, Ao_b, 64, 2048, 2048, 1 << 30);
    seg(Ad + (size_t)l * 64 * 8192, nullptr, Ad_b, 64, 8192, 8192, 1 << 30);
    cd.nseg = si; cd.total = ch;
    conv_k<<<(int)((ch + 255) / 256), 256, 0, stream>>>(cd, 2.0f);

    // x = rms(h, ln1); t = x@[Aq;Ak;Av].T (split-K) ; qkv = [x|t] @ Wqkv'^T
    rms_bf16_k<<<4096, 256, 0, stream>>>(hbuf, ln1 + l * 2048, xq, 2240);
    gemm_sk_k<<<dim3(32, 2, 4), 256, 0, stream>>>(xq, 2240, Aqkv_b, 2048, 192, 512, slab, 4096l * 192, 192);
    cvt_tail_k<<<3072, 256, 0, stream>>>(slab, 4096l * 192, 4, 192, xq, 2240, 2048);
    gemm8p_k<2240, 2240, 2240><<<dim3(16, 16), 512, 0, stream>>>(xq, Wqkv_b, qkvb, nullptr, 4096, 0, nullptr, 0);
    rope_k<<<dim3(4096, 6), 256, 0, stream>>>(qkvb, ct, st);
    attn_k<<<dim3(8, 16, 8), 256, 0, stream>>>(qkvb, amask, xo);
    // h += [o|t_o] @ Wo'^T  (small-N -> 2p, 512-block grid)
    gemm_sk_k<<<dim3(32, 1, 4), 256, 0, stream>>>(xo, 2112, Ao_b, 2048, 64, 512, slab, 4096l * 64, 64);
    cvt_tail_k<<<1024, 256, 0, stream>>>(slab, 4096l * 64, 4, 64, xo, 2112, 2048);
    gemm2p_k<2112, 2112, 2112, 1><<<dim3(32, 16), 256, 0, stream>>>(xo, Wo_b, nullptr, hbuf, 2048, nullptr, 0);
    // MLP: x row = [x(2048) | t_g(64) | t_u(64) | junk(64)] ld 2240; gate/up K=2240 via
    // zero weight tails (junk x 0 = 0, exact). gate/up on the single 8p instantiation.
    rms_bf16_k<<<4096, 256, 0, stream>>>(hbuf, ln2 + l * 2048, xq, 2240);
    gemm_sk_k<<<dim3(32, 1, 4), 256, 0, stream>>>(xq, 2240, Agu_b, 2048, 128, 512, slab, 4096l * 128, 128);
    cvt_tail_k<<<2048, 256, 0, stream>>>(slab, 4096l * 128, 4, 128, xq, 2240, 2048);
    gemm8p_k<2240, 2240, 2240><<<dim3(16, 32), 512, 0, stream>>>(xq, Wg_b, gbuf, nullptr, 8192, 0, nullptr, 0);
    gemm8p_k<2240, 2240, 2240><<<dim3(16, 32), 512, 0, stream>>>(xq, Wu_b, xd, nullptr, 8256, 2, gbuf, 8192);
    gemm_sk_k<<<dim3(32, 1, 8), 256, 0, stream>>>(xd, 8256, Ad_b, 8192, 64, 1024, slab, 4096l * 64, 64);
    cvt_tail_k<<<1024, 256, 0, stream>>>(slab, 4096l * 64, 8, 64, xd, 8256, 8192);
    gemm2p_k<8256, 8256, 8256, 1><<<dim3(32, 16), 256, 0, stream>>>(xd, Wd_b, nullptr, hbuf, 2048, nullptr, 0);
  }

  rms_f32_k<<<4096, 256, 0, stream>>>(hbuf, lnf, tmpf);
  pool_k<<<dim3(8, 8), 256, 0, stream>>>(tmpf, amask, pooled);
  proj_k<<<1536, 256, 0, stream>>>(pooled, projW, projb, embraw);
  norm_k<<<8, 256, 0, stream>>>(embraw, (float*)d_out);
}

// Round 12
// 2305.228 us; speedup vs baseline: 1.0587x; 1.0587x over previous
//
#include <hip/hip_runtime.h>

typedef __attribute__((ext_vector_type(8))) short short8;
typedef __attribute__((ext_vector_type(4))) float f32x4;

#define AS1 __attribute__((address_space(1)))
#define AS3 __attribute__((address_space(3)))

__device__ __forceinline__ unsigned short f2bf(float f) {
  unsigned int u = __float_as_uint(f);
  u = (u + 0x7fffu + ((u >> 16) & 1u)) >> 16;   // RNE
  return (unsigned short)u;
}
__device__ __forceinline__ float bf2f(unsigned short b) {
  return __uint_as_float(((unsigned int)b) << 16);
}

// ---------------- embedding gather ----------------
__global__ __launch_bounds__(256) void embed_k(const int* __restrict__ ids,
                                               const float* __restrict__ emb,
                                               float* __restrict__ h) {
  const int tok = blockIdx.x;
  const int id = ids[tok];
  const float4* s = (const float4*)(emb + (size_t)id * 2048);
  float4* d = (float4*)(h + (size_t)tok * 2048);
  d[threadIdx.x * 2] = s[threadIdx.x * 2];
  d[threadIdx.x * 2 + 1] = s[threadIdx.x * 2 + 1];
}

// ---------------- rope tables ----------------
__global__ __launch_bounds__(256) void ropetab_k(float* __restrict__ ct, float* __restrict__ st) {
  int i = blockIdx.x * 256 + threadIdx.x;  // 32768
  int pos = i >> 6, j = i & 63;
  float inv = __expf(-(float)j * (1.0f / 64.0f) * logf(500000.0f));
  float ang = (float)pos * inv;
  ct[i] = cosf(ang);
  st[i] = sinf(ang);
}

// ---------------- weight conversion fp32 -> bf16 with LoRA-B augmentation ----------------
struct ConvSeg {
  const float* W; const float* Bm; unsigned short* out;
  int N, Kin, Kout, bcol0; long chunk0;
};
struct ConvDesc { long total; int nseg; ConvSeg seg[16]; };

__global__ __launch_bounds__(256) void conv_k(ConvDesc d, float bscale) {
  long c = (long)blockIdx.x * 256 + threadIdx.x;
  if (c >= d.total) return;
  int si = 0;
  while (si + 1 < d.nseg && c >= d.seg[si + 1].chunk0) ++si;
  const float* W = d.seg[si].W;
  const float* Bm = d.seg[si].Bm;
  unsigned short* out = d.seg[si].out;
  const int Kin = d.seg[si].Kin, Kout = d.seg[si].Kout, bcol0 = d.seg[si].bcol0;
  long lc = c - d.seg[si].chunk0;
  int cpr = Kout >> 3;
  int row = (int)(lc / cpr);
  int col0 = ((int)(lc - (long)row * cpr)) << 3;
  union { unsigned short u[8]; uint4 v; } o;
  if (col0 < Kin) {
    const float4* src = (const float4*)(W + (size_t)row * Kin + col0);
    float4 a = src[0], b = src[1];
    o.u[0]=f2bf(a.x); o.u[1]=f2bf(a.y); o.u[2]=f2bf(a.z); o.u[3]=f2bf(a.w);
    o.u[4]=f2bf(b.x); o.u[5]=f2bf(b.y); o.u[6]=f2bf(b.z); o.u[7]=f2bf(b.w);
  } else {
    #pragma unroll
    for (int j = 0; j < 8; ++j) {
      int bj = col0 + j - bcol0;
      float v = (Bm && bj >= 0 && bj < 64) ? Bm[(size_t)row * 64 + bj] * bscale : 0.0f;
      o.u[j] = f2bf(v);
    }
  }
  *(uint4*)(out + (size_t)row * Kout + col0) = o.v;
}

// ---------------- RMSNorm (D=2048) -> bf16 row at stride ldx ----------------
__global__ __launch_bounds__(256) void rms_bf16_k(const float* __restrict__ h,
                                                  const float* __restrict__ w,
                                                  unsigned short* __restrict__ out, int ldx) {
  const int tok = blockIdx.x, t = threadIdx.x;
  const float4* row = (const float4*)(h + (size_t)tok * 2048);
  float4 v0 = row[t * 2], v1 = row[t * 2 + 1];
  float ss = v0.x*v0.x+v0.y*v0.y+v0.z*v0.z+v0.w*v0.w
           + v1.x*v1.x+v1.y*v1.y+v1.z*v1.z+v1.w*v1.w;
  #pragma unroll
  for (int x = 32; x > 0; x >>= 1) ss += __shfl_xor(ss, x, 64);
  __shared__ float sred[4];
  if ((t & 63) == 0) sred[t >> 6] = ss;
  __syncthreads();
  ss = sred[0] + sred[1] + sred[2] + sred[3];
  const float sc = rsqrtf(ss * (1.0f / 2048.0f) + 1e-5f);
  const int d0 = t * 8;
  const float vals[8] = {v0.x, v0.y, v0.z, v0.w, v1.x, v1.y, v1.z, v1.w};
  union { unsigned short u[8]; uint4 v; } o;
  #pragma unroll
  for (int j = 0; j < 8; ++j) o.u[j] = f2bf(vals[j] * sc * w[d0 + j]);
  *(uint4*)(out + (size_t)tok * ldx + d0) = o.v;
}

// ---------------- final RMSNorm -> fp32 ----------------
__global__ __launch_bounds__(256) void rms_f32_k(const float* __restrict__ h,
                                                 const float* __restrict__ w,
                                                 float* __restrict__ out) {
  const int tok = blockIdx.x, t = threadIdx.x;
  const float4* row = (const float4*)(h + (size_t)tok * 2048);
  float4 v0 = row[t * 2], v1 = row[t * 2 + 1];
  float ss = v0.x*v0.x+v0.y*v0.y+v0.z*v0.z+v0.w*v0.w
           + v1.x*v1.x+v1.y*v1.y+v1.z*v1.z+v1.w*v1.w;
  #pragma unroll
  for (int x = 32; x > 0; x >>= 1) ss += __shfl_xor(ss, x, 64);
  __shared__ float sred[4];
  if ((t & 63) == 0) sred[t >> 6] = ss;
  __syncthreads();
  ss = sred[0] + sred[1] + sred[2] + sred[3];
  const float sc = rsqrtf(ss * (1.0f / 2048.0f) + 1e-5f);
  const int d0 = t * 8;
  float4 o0, o1;
  o0.x = v0.x * sc * w[d0 + 0]; o0.y = v0.y * sc * w[d0 + 1];
  o0.z = v0.z * sc * w[d0 + 2]; o0.w = v0.w * sc * w[d0 + 3];
  o1.x = v1.x * sc * w[d0 + 4]; o1.y = v1.y * sc * w[d0 + 5];
  o1.z = v1.z * sc * w[d0 + 6]; o1.w = v1.w * sc * w[d0 + 7];
  float4* op = (float4*)(out + (size_t)tok * 2048 + d0);
  op[0] = o0; op[1] = o1;
}

// ---------------- split-K LoRA GEMM: f32 partial slabs (no atomics) ----------------
__global__ __launch_bounds__(256) void gemm_sk_k(
    const unsigned short* __restrict__ A, int lda,
    const unsigned short* __restrict__ B, int ldb, int Nb, int KS,
    float* __restrict__ Cf, long slabStride, int ldc) {
  __shared__ unsigned short As[128 * 64];
  __shared__ unsigned short Bs[128 * 64];
  const int t = threadIdx.x;
  const int w = t >> 6, l = t & 63;
  const int lr = l & 15, lg = l >> 4;
  const int m0 = blockIdx.x * 128;
  const int n0 = blockIdx.y * 128;
  const int wr = (w >> 1) * 64, wc = (w & 1) * 64;
  const int koff = blockIdx.z * KS;

  const f32x4 vzero = {0.f, 0.f, 0.f, 0.f};
  f32x4 acc[4][4];
  #pragma unroll
  for (int i = 0; i < 4; ++i)
    #pragma unroll
    for (int j = 0; j < 4; ++j) acc[i][j] = vzero;

  const int scol = ((t & 7) ^ ((t >> 3) & 7)) * 8;
  const unsigned short* aSrc = A + (size_t)(m0 + (t >> 3)) * lda + koff + scol;
  const int bRow0 = n0 + (t >> 3);

  for (int k0 = 0; k0 < KS; k0 += 64) {
    __syncthreads();
    #pragma unroll
    for (int i = 0; i < 4; ++i) {
      __builtin_amdgcn_global_load_lds((const AS1 void*)(aSrc + (size_t)i * 32 * lda + k0),
                                       (AS3 void*)(As + i * 2048 + w * 512), 16, 0, 0);
      int br = bRow0 + i * 32; br = br < Nb ? br : Nb - 1;
      __builtin_amdgcn_global_load_lds((const AS1 void*)(B + (size_t)br * ldb + koff + k0 + scol),
                                       (AS3 void*)(Bs + i * 2048 + w * 512), 16, 0, 0);
    }
    __syncthreads();
    #pragma unroll
    for (int kk = 0; kk < 64; kk += 32) {
      const int swz = ((lg + (kk >> 3)) ^ (lr & 7)) << 3;
      short8 af[4], bfr[4];
      #pragma unroll
      for (int i = 0; i < 4; ++i)
        af[i] = *(const short8*)&As[(wr + i * 16 + lr) * 64 + swz];
      #pragma unroll
      for (int j = 0; j < 4; ++j)
        bfr[j] = *(const short8*)&Bs[(wc + j * 16 + lr) * 64 + swz];
      #pragma unroll
      for (int i = 0; i < 4; ++i)
        #pragma unroll
        for (int j = 0; j < 4; ++j)
          acc[i][j] = __builtin_amdgcn_mfma_f32_16x16x32_bf16(af[i], bfr[j], acc[i][j], 0, 0, 0);
    }
  }

  float* slab = Cf + (size_t)blockIdx.z * slabStride;
  #pragma unroll
  for (int i = 0; i < 4; ++i) {
    const int row = m0 + wr + i * 16 + lg * 4;
    #pragma unroll
    for (int j = 0; j < 4; ++j) {
      const int col = n0 + wc + j * 16 + lr;
      if (col < Nb) {
        #pragma unroll
        for (int r = 0; r < 4; ++r)
          slab[(size_t)(row + r) * ldc + col] = acc[i][j][r];
      }
    }
  }
}

// ---------------- sum split-K slabs -> bf16 tail columns ----------------
__global__ __launch_bounds__(256) void cvt_tail_k(const float* __restrict__ slab,
                                                  long slabStride, int S, int N,
                                                  unsigned short* __restrict__ out,
                                                  int ldx, int col0) {
  int i = blockIdx.x * 256 + threadIdx.x;
  if (i >= 4096 * N) return;
  int row = i / N, col = i - row * N;
  float s = 0.f;
  for (int z = 0; z < S; ++z) s += slab[(size_t)z * slabStride + (size_t)row * N + col];
  out[(size_t)row * ldx + col0 + col] = f2bf(s);
}

// ---------------- big GEMM (r10 config): 256x256, K-half ring, counted vmcnt, runtime K ----------------
// SINGLE NON-TEMPLATE SYMBOL (runtime K/lda/ldb/epi) — best stable config (r10: 256us
// gate/up, total 2307). epi 0: Cb=bf16(acc); 1: Cf+=acc; 2: Cb=bf16(silu(G)*acc).
__global__ __launch_bounds__(512, 2) void gemm8p_k(
    const unsigned short* __restrict__ A, int lda,
    const unsigned short* __restrict__ B, int ldb, int K,
    unsigned short* __restrict__ Cb, float* __restrict__ Cf, int ldc, int epi,
    const unsigned short* __restrict__ G, int ldg) {
  __shared__ __attribute__((aligned(16))) unsigned short As[4][256 * 32];
  __shared__ __attribute__((aligned(16))) unsigned short Bs[4][256 * 32];
  const int t = threadIdx.x;
  const int w = t >> 6, l = t & 63;
  const int lr = l & 15, lg = l >> 4;

  const int gy = gridDim.y;
  int flat = blockIdx.x + gridDim.x * blockIdx.y;
  const int cpx = (gridDim.x * gy) >> 3;
  flat = (flat & 7) * cpx + (flat >> 3);
  const int m0 = (flat / gy) * 256;
  const int n0 = (flat % gy) * 256;

  const int wr = (w >> 2) * 128;
  const int wc = (w & 3) * 64;

  const f32x4 vzero = {0.f, 0.f, 0.f, 0.f};
  f32x4 acc[8][4];
  #pragma unroll
  for (int i = 0; i < 8; ++i)
    #pragma unroll
    for (int j = 0; j < 4; ++j) acc[i][j] = vzero;

  const int x = (l & 7) ^ (l >> 3);
  const int srow = w * 32 + 2 * (l >> 3) + (x >> 2);
  const int scol = (x & 3) * 8;
  const unsigned short* aS0 = A + (size_t)(m0 + srow) * lda + scol;
  const unsigned short* aS1 = aS0 + (size_t)16 * lda;
  const unsigned short* bS0 = B + (size_t)(n0 + srow) * ldb + scol;
  const unsigned short* bS1 = bS0 + (size_t)16 * ldb;
  char* AsD = (char*)&As[0][0] + w * 2048;
  char* BsD = (char*)&Bs[0][0] + w * 2048;

  auto stA = [&](int slot, int kb) {
    __builtin_amdgcn_global_load_lds((const AS1 void*)(aS0 + kb),
                                     (AS3 void*)(AsD + slot * 16384), 16, 0, 0);
    __builtin_amdgcn_global_load_lds((const AS1 void*)(aS1 + kb),
                                     (AS3 void*)(AsD + slot * 16384 + 1024), 16, 0, 0);
  };
  auto stB = [&](int slot, int kb) {
    __builtin_amdgcn_global_load_lds((const AS1 void*)(bS0 + kb),
                                     (AS3 void*)(BsD + slot * 16384), 16, 0, 0);
    __builtin_amdgcn_global_load_lds((const AS1 void*)(bS1 + kb),
                                     (AS3 void*)(BsD + slot * 16384 + 1024), 16, 0, 0);
  };

  const int rdoff = (lr >> 1) * 128 + (((lg | ((lr & 1) << 2)) ^ (lr >> 1)) << 4);
  #define RD(arr, slot, Rb) \
    (*(const short8*)((const char*)(arr) + (slot) * 16384 + (Rb) * 64 + rdoff))

  stA(0, 0); stB(0, 0);
  stA(1, 32); stB(1, 32);
  asm volatile("s_waitcnt vmcnt(4)" ::: "memory");
  __builtin_amdgcn_s_barrier();

  const int NT = K >> 6;
  short8 a0[4], a1[4], b0[4], b1[4];

  for (int tt = 0; tt < NT; ++tt) {
    const int g0 = 2 * tt;
    const int s0 = g0 & 3, s1 = (g0 + 1) & 3, vA = (g0 + 2) & 3, vB = (g0 + 3) & 3;
    const bool pf = (tt + 1 < NT);
    const int kbN = pf ? (tt + 1) * 64 : 0;

    // ---- P0 ----
    #pragma unroll
    for (int i = 0; i < 4; ++i) a0[i] = RD(As, s0, wr + i * 16);
    #pragma unroll
    for (int j = 0; j < 4; ++j) b0[j] = RD(Bs, s0, wc + j * 16);
    if (pf) stA(vA, kbN);
    __builtin_amdgcn_s_barrier();
    asm volatile("s_waitcnt lgkmcnt(0)" ::: "memory");
    __builtin_amdgcn_s_setprio(1);
    #pragma unroll
    for (int i = 0; i < 4; ++i)
      #pragma unroll
      for (int j = 0; j < 4; ++j)
        acc[i][j] = __builtin_amdgcn_mfma_f32_16x16x32_bf16(a0[i], b0[j], acc[i][j], 0, 0, 0);
    __builtin_amdgcn_s_setprio(0);
    __builtin_amdgcn_s_barrier();

    // ---- P1 ----
    #pragma unroll
    for (int i = 0; i < 4; ++i) a1[i] = RD(As, s0, wr + 64 + i * 16);
    if (pf) {
      stB(vA, kbN);
      asm volatile("s_waitcnt vmcnt(4)" ::: "memory");
    } else {
      asm volatile("s_waitcnt vmcnt(0)" ::: "memory");
    }
    __builtin_amdgcn_s_barrier();
    asm volatile("s_waitcnt lgkmcnt(0)" ::: "memory");
    __builtin_amdgcn_s_setprio(1);
    #pragma unroll
    for (int i = 0; i < 4; ++i)
      #pragma unroll
      for (int j = 0; j < 4; ++j)
        acc[i + 4][j] = __builtin_amdgcn_mfma_f32_16x16x32_bf16(a1[i], b0[j], acc[i + 4][j], 0, 0, 0);
    __builtin_amdgcn_s_setprio(0);
    __builtin_amdgcn_s_barrier();

    // ---- P2 ----
    #pragma unroll
    for (int i = 0; i < 4; ++i) a0[i] = RD(As, s1, wr + i * 16);
    #pragma unroll
    for (int j = 0; j < 4; ++j) b1[j] = RD(Bs, s1, wc + j * 16);
    if (pf) stA(vB, kbN + 32);
    __builtin_amdgcn_s_barrier();
    asm volatile("s_waitcnt lgkmcnt(0)" ::: "memory");
    __builtin_amdgcn_s_setprio(1);
    #pragma unroll
    for (int i = 0; i < 4; ++i)
      #pragma unroll
      for (int j = 0; j < 4; ++j)
        acc[i][j] = __builtin_amdgcn_mfma_f32_16x16x32_bf16(a0[i], b1[j], acc[i][j], 0, 0, 0);
    __builtin_amdgcn_s_setprio(0);
    __builtin_amdgcn_s_barrier();

    // ---- P3 ----
    #pragma unroll
    for (int i = 0; i < 4; ++i) a1[i] = RD(As, s1, wr + 64 + i * 16);
    if (pf) {
      stB(vB, kbN + 32);
      asm volatile("s_waitcnt vmcnt(4)" ::: "memory");
    } else {
      asm volatile("s_waitcnt vmcnt(0)" ::: "memory");
    }
    __builtin_amdgcn_s_barrier();
    asm volatile("s_waitcnt lgkmcnt(0)" ::: "memory");
    __builtin_amdgcn_s_setprio(1);
    #pragma unroll
    for (int i = 0; i < 4; ++i)
      #pragma unroll
      for (int j = 0; j < 4; ++j)
        acc[i + 4][j] = __builtin_amdgcn_mfma_f32_16x16x32_bf16(a1[i], b1[j], acc[i + 4][j], 0, 0, 0);
    __builtin_amdgcn_s_setprio(0);
    __builtin_amdgcn_s_barrier();
  }
  #undef RD

  #pragma unroll
  for (int i = 0; i < 8; ++i) {
    const int row = m0 + wr + i * 16 + lg * 4;
    #pragma unroll
    for (int j = 0; j < 4; ++j) {
      const int col = n0 + wc + j * 16 + lr;
      #pragma unroll
      for (int r = 0; r < 4; ++r) {
        float v = acc[i][j][r];
        size_t off = (size_t)(row + r) * ldc + col;
        if (epi == 0) {
          Cb[off] = f2bf(v);
        } else if (epi == 1) {
          Cf[off] += v;
        } else {
          float g = bf2f(G[(size_t)(row + r) * ldg + col]);
          Cb[off] = f2bf(g / (1.0f + __expf(-g)) * v);
        }
      }
    }
  }
}

// ---------------- 2p GEMM (small-N shapes, 512-block grids): 128x128, dbuf, swizzle ----------------
template<int K_, int LDA_, int LDB_, int EPI_>
__global__ __launch_bounds__(256) void gemm2p_k(
    const unsigned short* __restrict__ A,
    const unsigned short* __restrict__ B,
    unsigned short* __restrict__ Cb, float* __restrict__ Cf, int ldc,
    const unsigned short* __restrict__ G, int ldg) {
  __shared__ unsigned short As[2][128 * 64];
  __shared__ unsigned short Bs[2][128 * 64];
  const int t = threadIdx.x;
  const int w = t >> 6, l = t & 63;
  const int lr = l & 15, lg = l >> 4;

  const int gx = gridDim.x;
  int flat = blockIdx.x + gx * blockIdx.y;
  const int cpx = (gx * gridDim.y) >> 3;
  flat = (flat & 7) * cpx + (flat >> 3);
  const int m0 = (flat % gx) * 128;
  const int n0 = (flat / gx) * 128;

  const int wr = (w >> 1) * 64, wc = (w & 1) * 64;

  const f32x4 vzero = {0.f, 0.f, 0.f, 0.f};
  f32x4 acc[4][4];
  #pragma unroll
  for (int i = 0; i < 4; ++i)
    #pragma unroll
    for (int j = 0; j < 4; ++j) acc[i][j] = vzero;

  const int scol = ((t & 7) ^ ((t >> 3) & 7)) * 8;
  const unsigned short* aSrc = A + (size_t)(m0 + (t >> 3)) * LDA_ + scol;
  const unsigned short* bSrc = B + (size_t)(n0 + (t >> 3)) * LDB_ + scol;

  auto stage = [&](int buf, int k0) {
    #pragma unroll
    for (int i = 0; i < 4; ++i) {
      __builtin_amdgcn_global_load_lds((const AS1 void*)(aSrc + (size_t)i * 32 * LDA_ + k0),
                                       (AS3 void*)(&As[buf][i * 2048 + w * 512]), 16, 0, 0);
      __builtin_amdgcn_global_load_lds((const AS1 void*)(bSrc + (size_t)i * 32 * LDB_ + k0),
                                       (AS3 void*)(&Bs[buf][i * 2048 + w * 512]), 16, 0, 0);
    }
  };

  constexpr int NT = K_ / 64;
  stage(0, 0);
  __syncthreads();

  int cur = 0;
  for (int kt = 0; kt < NT; ++kt) {
    if (kt + 1 < NT) stage(cur ^ 1, (kt + 1) * 64);
    #pragma unroll
    for (int kk = 0; kk < 64; kk += 32) {
      const int swz = ((lg + (kk >> 3)) ^ (lr & 7)) << 3;
      short8 af[4], bfr[4];
      #pragma unroll
      for (int i = 0; i < 4; ++i)
        af[i] = *(const short8*)&As[cur][(wr + i * 16 + lr) * 64 + swz];
      #pragma unroll
      for (int j = 0; j < 4; ++j)
        bfr[j] = *(const short8*)&Bs[cur][(wc + j * 16 + lr) * 64 + swz];
      #pragma unroll
      for (int i = 0; i < 4; ++i)
        #pragma unroll
        for (int j = 0; j < 4; ++j)
          acc[i][j] = __builtin_amdgcn_mfma_f32_16x16x32_bf16(af[i], bfr[j], acc[i][j], 0, 0, 0);
    }
    __syncthreads();
    cur ^= 1;
  }

  #pragma unroll
  for (int i = 0; i < 4; ++i) {
    const int row = m0 + wr + i * 16 + lg * 4;
    #pragma unroll
    for (int j = 0; j < 4; ++j) {
      const int col = n0 + wc + j * 16 + lr;
      #pragma unroll
      for (int r = 0; r < 4; ++r) {
        float v = acc[i][j][r];
        size_t off = (size_t)(row + r) * ldc + col;
        if constexpr (EPI_ == 0) {
          Cb[off] = f2bf(v);
        } else if constexpr (EPI_ == 1) {
          Cf[off] += v;
        } else {
          float g = bf2f(G[(size_t)(row + r) * ldg + col]);
          Cb[off] = f2bf(g / (1.0f + __expf(-g)) * v);
        }
      }
    }
  }
}

// ---------------- RoPE in-place on qkv buffer ----------------
__global__ __launch_bounds__(256) void rope_k(unsigned short* __restrict__ qkv,
                                              const float* __restrict__ ct,
                                              const float* __restrict__ st) {
  const int tok = blockIdx.x;
  const int pid = blockIdx.y * 256 + threadIdx.x;  // 0..1535
  const int head = pid >> 6, j = pid & 63;
  const int s = tok & 511;
  unsigned short* base = qkv + (size_t)tok * 4096 + (head < 16 ? head * 128 : 2048 + (head - 16) * 128);
  const float c = ct[s * 64 + j], sn = st[s * 64 + j];
  const float x1 = bf2f(base[j]), x2 = bf2f(base[j + 64]);
  base[j] = f2bf(x1 * c - x2 * sn);
  base[j + 64] = f2bf(x2 * c + x1 * sn);
}

// ---------------- flash attention (K direct from global/L2; V transposed via LDS) ----------------
// K/V per (b,kvh) = 128KB each -> L2/L3-resident (lesson-7: don't LDS-stage cache-fit data).
// QK^T B-fragments load straight from global; only V (needs transpose) and P stay in LDS.
__global__ __launch_bounds__(256) void attn_k(const unsigned short* __restrict__ qkv,
                                              const int* __restrict__ amask,
                                              unsigned short* __restrict__ xo) {
  const int q0 = blockIdx.x * 64;
  const int hh = blockIdx.y;
  const int b = blockIdx.z;
  const int kvh = hh >> 1;
  const int t = threadIdx.x, w = t >> 6, l = t & 63;
  const int lr = l & 15, lg = l >> 4;

  const size_t rowbase = (size_t)b * 512 * 4096;
  const unsigned short* Q = qkv + rowbase + hh * 128;
  const unsigned short* Kp = qkv + rowbase + 2048 + kvh * 128;
  const unsigned short* Vp = qkv + rowbase + 3072 + kvh * 128;

  __shared__ unsigned short Vt[128 * 32];
  __shared__ unsigned short Ps[4][16 * 32];

  short8 qf[4];
  const unsigned short* qrow = Q + (size_t)(q0 + w * 16 + lr) * 4096;
  #pragma unroll
  for (int kk = 0; kk < 4; ++kk) qf[kk] = *(const short8*)(qrow + kk * 32 + lg * 8);

  const f32x4 vzero = {0.f, 0.f, 0.f, 0.f};
  f32x4 accO[8];
  #pragma unroll
  for (int i = 0; i < 8; ++i) accO[i] = vzero;
  float mrow[4], lrow[4];
  #pragma unroll
  for (int r = 0; r < 4; ++r) { mrow[r] = -1e30f; lrow[r] = 0.f; }

  const int qpos0 = q0 + w * 16 + lg * 4;
  const int ktiles = (q0 + 64) >> 5;
  for (int kt = 0; kt < ktiles; ++kt) {
    const int kbase = kt * 32;

    // QK^T: K fragments direct from global (L2-hit); no LDS dependency
    f32x4 sf[2]; sf[0] = vzero; sf[1] = vzero;
    #pragma unroll
    for (int nt = 0; nt < 2; ++nt)
      #pragma unroll
      for (int kk = 0; kk < 4; ++kk) {
        short8 kf = *(const short8*)(Kp + (size_t)(kbase + nt * 16 + lr) * 4096 + kk * 32 + lg * 8);
        sf[nt] = __builtin_amdgcn_mfma_f32_16x16x32_bf16(qf[kk], kf, sf[nt], 0, 0, 0);
      }

    // softmax (VALU only — overlaps other waves' Vt/PV work)
    float pv[2][4], pmax[4];
    #pragma unroll
    for (int r = 0; r < 4; ++r) pmax[r] = -1e30f;
    #pragma unroll
    for (int nt = 0; nt < 2; ++nt) {
      const int key = kbase + nt * 16 + lr;
      const bool okm = amask[b * 512 + key] != 0;
      #pragma unroll
      for (int r = 0; r < 4; ++r) {
        float s = sf[nt][r] * 0.08838834764831845f;
        if (!okm || key > qpos0 + r) s = -1e9f;
        pv[nt][r] = s;
        pmax[r] = fmaxf(pmax[r], s);
      }
    }
    #pragma unroll
    for (int x = 1; x < 16; x <<= 1)
      #pragma unroll
      for (int r = 0; r < 4; ++r) pmax[r] = fmaxf(pmax[r], __shfl_xor(pmax[r], x, 64));

    float alpha[4];
    #pragma unroll
    for (int r = 0; r < 4; ++r) {
      float mn = fmaxf(mrow[r], pmax[r]);
      alpha[r] = __expf(mrow[r] - mn);
      mrow[r] = mn;
    }
    float rowsum[4];
    #pragma unroll
    for (int r = 0; r < 4; ++r) {
      float p0 = __expf(pv[0][r] - mrow[r]);
      float p1 = __expf(pv[1][r] - mrow[r]);
      pv[0][r] = p0; pv[1][r] = p1;
      rowsum[r] = p0 + p1;
    }
    #pragma unroll
    for (int x = 1; x < 16; x <<= 1)
      #pragma unroll
      for (int r = 0; r < 4; ++r) rowsum[r] += __shfl_xor(rowsum[r], x, 64);
    #pragma unroll
    for (int r = 0; r < 4; ++r) lrow[r] = lrow[r] * alpha[r] + rowsum[r];
    #pragma unroll
    for (int nt = 0; nt < 8; ++nt)
      #pragma unroll
      for (int r = 0; r < 4; ++r) accO[nt][r] *= alpha[r];

    __syncthreads();   // all waves done reading prev tile's Vt

    // stage V^T for this tile
    #pragma unroll
    for (int c = 0; c < 2; ++c) {
      int chunk = c * 256 + t;
      int key = chunk >> 4, ch = chunk & 15;
      short8 v = *(const short8*)(Vp + (size_t)(kbase + key) * 4096 + ch * 8);
      #pragma unroll
      for (int j = 0; j < 8; ++j) Vt[(ch * 8 + j) * 32 + key] = ((const unsigned short*)&v)[j];
    }
    // P (D-layout) -> per-warp LDS -> A-layout
    #pragma unroll
    for (int nt = 0; nt < 2; ++nt)
      #pragma unroll
      for (int r = 0; r < 4; ++r)
        Ps[w][(lg * 4 + r) * 32 + nt * 16 + lr] = f2bf(pv[nt][r]);
    __syncthreads();   // Vt published

    short8 pa = *(const short8*)&Ps[w][lr * 32 + lg * 8];
    #pragma unroll
    for (int nt = 0; nt < 8; ++nt) {
      short8 vb = *(const short8*)&Vt[(nt * 16 + lr) * 32 + lg * 8];
      accO[nt] = __builtin_amdgcn_mfma_f32_16x16x32_bf16(pa, vb, accO[nt], 0, 0, 0);
    }
  }

  const size_t tokbase = ((size_t)b * 512 + qpos0) * 2112;
  #pragma unroll
  for (int nt = 0; nt < 8; ++nt) {
    const int col = hh * 128 + nt * 16 + lr;
    #pragma unroll
    for (int r = 0; r < 4; ++r)
      xo[tokbase + (size_t)r * 2112 + col] = f2bf(accO[nt][r] / lrow[r]);
  }
}

// ---------------- masked mean pool ----------------
__global__ __launch_bounds__(256) void pool_k(const float* __restrict__ tmpf,
                                              const int* __restrict__ amask,
                                              float* __restrict__ pooled) {
  const int b = blockIdx.y;
  const int d = blockIdx.x * 256 + threadIdx.x;
  float acc = 0.f, ms = 0.f;
  for (int s = 0; s < 512; ++s) {
    float m = (float)amask[b * 512 + s];
    acc += tmpf[((size_t)b * 512 + s) * 2048 + d] * m;
    ms += m;
  }
  pooled[b * 2048 + d] = acc / fmaxf(ms, 1e-9f);
}

// ---------------- projection ----------------
__global__ __launch_bounds__(256) void proj_k(const float* __restrict__ pooled,
                                              const float* __restrict__ W,
                                              const float* __restrict__ bias,
                                              float* __restrict__ emb) {
  const int idx = blockIdx.x * 4 + (threadIdx.x >> 6);
  const int l = threadIdx.x & 63;
  const int b = idx / 768, pcol = idx - b * 768;
  const float* x = pooled + b * 2048;
  const float* wr = W + (size_t)pcol * 2048;
  float acc = 0.f;
  #pragma unroll
  for (int i = 0; i < 32; ++i) acc += x[l + i * 64] * wr[l + i * 64];
  #pragma unroll
  for (int xm = 32; xm > 0; xm >>= 1) acc += __shfl_xor(acc, xm, 64);
  if (l == 0) emb[b * 768 + pcol] = acc + bias[pcol];
}

// ---------------- L2 normalize ----------------
__global__ __launch_bounds__(256) void norm_k(const float* __restrict__ emb, float* __restrict__ out) {
  const int b = blockIdx.x, t = threadIdx.x;
  float v[3]; float ss = 0.f;
  #pragma unroll
  for (int i = 0; i < 3; ++i) { v[i] = emb[b * 768 + t + i * 256]; ss += v[i] * v[i]; }
  #pragma unroll
  for (int x = 32; x > 0; x >>= 1) ss += __shfl_xor(ss, x, 64);
  __shared__ float sred[4];
  if ((t & 63) == 0) sred[t >> 6] = ss;
  __syncthreads();
  ss = sred[0] + sred[1] + sred[2] + sred[3];
  const float inv = 1.0f / fmaxf(sqrtf(ss), 1e-12f);
  #pragma unroll
  for (int i = 0; i < 3; ++i) out[b * 768 + t + i * 256] = v[i] * inv;
}

extern "C" void kernel_launch(void* const* d_in, const int* in_sizes, int n_in,
                              void* d_out, int out_size, void* d_ws, size_t ws_size,
                              hipStream_t stream) {
  const int* ids = (const int*)d_in[0];
  const int* amask = (const int*)d_in[1];
  const float* tok_emb = (const float*)d_in[2];
  const float* Wq = (const float*)d_in[3];
  const float* Wk = (const float*)d_in[4];
  const float* Wv = (const float*)d_in[5];
  const float* Wo = (const float*)d_in[6];
  const float* Wg = (const float*)d_in[7];
  const float* Wu = (const float*)d_in[8];
  const float* Wd = (const float*)d_in[9];
  const float* Aq = (const float*)d_in[10];
  const float* Bq = (const float*)d_in[11];
  const float* Ak = (const float*)d_in[12];
  const float* Bk = (const float*)d_in[13];
  const float* Av = (const float*)d_in[14];
  const float* Bv = (const float*)d_in[15];
  const float* Ao = (const float*)d_in[16];
  const float* Bo = (const float*)d_in[17];
  const float* Ag = (const float*)d_in[18];
  const float* Bg = (const float*)d_in[19];
  const float* Au = (const float*)d_in[20];
  const float* Bu = (const float*)d_in[21];
  const float* Ad = (const float*)d_in[22];
  const float* Bd = (const float*)d_in[23];
  const float* ln1 = (const float*)d_in[24];
  const float* ln2 = (const float*)d_in[25];
  const float* lnf = (const float*)d_in[26];
  const float* projW = (const float*)d_in[27];
  const float* projb = (const float*)d_in[28];

  typedef unsigned short u16;
  char* p = (char*)d_ws;
  auto take = [&](size_t n) { char* r = p; p += (n + 255) & ~(size_t)255; return r; };
  u16* Wqkv_b = (u16*)take(4096ull * 2240 * 2);
  u16* Wo_b   = (u16*)take(2048ull * 2112 * 2);
  u16* Wg_b   = (u16*)take(8192ull * 2112 * 2);
  u16* Wu_b   = (u16*)take(8192ull * 2176 * 2);
  u16* Wd_b   = (u16*)take(2048ull * 8256 * 2);
  u16* Aqkv_b = (u16*)take(192ull * 2048 * 2);
  u16* Agu_b  = (u16*)take(128ull * 2048 * 2);
  u16* Ao_b   = (u16*)take(64ull * 2048 * 2);
  u16* Ad_b   = (u16*)take(64ull * 8192 * 2);
  float* hbuf = (float*)take(4096ull * 2048 * 4);
  u16* xq     = (u16*)take(4096ull * 2240 * 2);
  u16* xo     = (u16*)take(4096ull * 2112 * 2);
  u16* xd     = (u16*)take(4096ull * 8256 * 2);
  u16* qkvb   = (u16*)take(4096ull * 4096 * 2);
  u16* gbuf   = (u16*)take(4096ull * 8192 * 2);
  float* ct   = (float*)take(512ull * 64 * 4);
  float* st   = (float*)take(512ull * 64 * 4);
  float* pooled = (float*)take(8ull * 2048 * 4);
  float* embraw = (float*)take(8ull * 768 * 4);
  float* tmpf = (float*)gbuf;
  float* slab = (float*)gbuf;   // split-K partials; stream-ordered reuse of gbuf
  (void)ws_size; (void)in_sizes; (void)n_in; (void)out_size;

  embed_k<<<4096, 256, 0, stream>>>(ids, tok_emb, hbuf);
  ropetab_k<<<128, 256, 0, stream>>>(ct, st);

  for (int l = 0; l < 2; ++l) {
    ConvDesc cd;
    long ch = 0; int si = 0;
    auto seg = [&](const float* W, const float* Bm, u16* out, int N, int Kin, int Kout, int bcol0) {
      cd.seg[si].W = W; cd.seg[si].Bm = Bm; cd.seg[si].out = out;
      cd.seg[si].N = N; cd.seg[si].Kin = Kin; cd.seg[si].Kout = Kout;
      cd.seg[si].bcol0 = bcol0; cd.seg[si].chunk0 = ch;
      ch += (long)N * (Kout >> 3); ++si;
    };
    seg(Wq + (size_t)l * 2048 * 2048, Bq + (size_t)l * 2048 * 64, Wqkv_b,               2048, 2048, 2240, 2048);
    seg(Wk + (size_t)l * 1024 * 2048, Bk + (size_t)l * 1024 * 64, Wqkv_b + 2048ull * 2240, 1024, 2048, 2240, 2112);
    seg(Wv + (size_t)l * 1024 * 2048, Bv + (size_t)l * 1024 * 64, Wqkv_b + 3072ull * 2240, 1024, 2048, 2240, 2176);
    seg(Wo + (size_t)l * 2048 * 2048, Bo + (size_t)l * 2048 * 64, Wo_b, 2048, 2048, 2112, 2048);
    seg(Wg + (size_t)l * 8192 * 2048, Bg + (size_t)l * 8192 * 64, Wg_b, 8192, 2048, 2112, 2048);
    seg(Wu + (size_t)l * 8192 * 2048, Bu + (size_t)l * 8192 * 64, Wu_b, 8192, 2048, 2176, 2112);
    seg(Wd + (size_t)l * 2048 * 8192, Bd + (size_t)l * 2048 * 64, Wd_b, 2048, 8192, 8256, 8192);
    seg(Aq + (size_t)l * 64 * 2048, nullptr, Aqkv_b,                64, 2048, 2048, 1 << 30);
    seg(Ak + (size_t)l * 64 * 2048, nullptr, Aqkv_b + 64ull * 2048, 64, 2048, 2048, 1 << 30);
    seg(Av + (size_t)l * 64 * 2048, nullptr, Aqkv_b + 128ull * 2048, 64, 2048, 2048, 1 << 30);
    seg(Ag + (size_t)l * 64 * 2048, nullptr, Agu_b,                 64, 2048, 2048, 1 << 30);
    seg(Au + (size_t)l * 64 * 2048, nullptr, Agu_b + 64ull * 2048,  64, 2048, 2048, 1 << 30);
    seg(Ao + (size_t)l * 64 * 2048, nullptr, Ao_b, 64, 2048, 2048, 1 << 30);
    seg(Ad + (size_t)l * 64 * 8192, nullptr, Ad_b, 64, 8192, 8192, 1 << 30);
    cd.nseg = si; cd.total = ch;
    conv_k<<<(int)((ch + 255) / 256), 256, 0, stream>>>(cd, 2.0f);

    // x = rms(h, ln1); t = x@[Aq;Ak;Av].T (split-K) ; qkv = [x|t] @ Wqkv'^T
    rms_bf16_k<<<4096, 256, 0, stream>>>(hbuf, ln1 + l * 2048, xq, 2240);
    gemm_sk_k<<<dim3(32, 2, 4), 256, 0, stream>>>(xq, 2240, Aqkv_b, 2048, 192, 512, slab, 4096l * 192, 192);
    cvt_tail_k<<<3072, 256, 0, stream>>>(slab, 4096l * 192, 4, 192, xq, 2240, 2048);
    gemm8p_k<<<dim3(16, 16), 512, 0, stream>>>(xq, 2240, Wqkv_b, 2240, 2240, qkvb, nullptr, 4096, 0, nullptr, 0);
    rope_k<<<dim3(4096, 6), 256, 0, stream>>>(qkvb, ct, st);
    attn_k<<<dim3(8, 16, 8), 256, 0, stream>>>(qkvb, amask, xo);
    // h += [o|t_o] @ Wo'^T  (small-N -> 2p, 512-block grid)
    gemm_sk_k<<<dim3(32, 1, 4), 256, 0, stream>>>(xo, 2112, Ao_b, 2048, 64, 512, slab, 4096l * 64, 64);
    cvt_tail_k<<<1024, 256, 0, stream>>>(slab, 4096l * 64, 4, 64, xo, 2112, 2048);
    gemm2p_k<2112, 2112, 2112, 1><<<dim3(32, 16), 256, 0, stream>>>(xo, Wo_b, nullptr, hbuf, 2048, nullptr, 0);
    // MLP: gate/up on unified 8p (512-block grids), down on 2p (512-block grid)
    rms_bf16_k<<<4096, 256, 0, stream>>>(hbuf, ln2 + l * 2048, xq, 2176);
    gemm_sk_k<<<dim3(32, 1, 4), 256, 0, stream>>>(xq, 2176, Agu_b, 2048, 128, 512, slab, 4096l * 128, 128);
    cvt_tail_k<<<2048, 256, 0, stream>>>(slab, 4096l * 128, 4, 128, xq, 2176, 2048);
    gemm8p_k<<<dim3(16, 32), 512, 0, stream>>>(xq, 2176, Wg_b, 2112, 2112, gbuf, nullptr, 8192, 0, nullptr, 0);
    gemm8p_k<<<dim3(16, 32), 512, 0, stream>>>(xq, 2176, Wu_b, 2176, 2176, xd, nullptr, 8256, 2, gbuf, 8192);
    gemm_sk_k<<<dim3(32, 1, 8), 256, 0, stream>>>(xd, 8256, Ad_b, 8192, 64, 1024, slab, 4096l * 64, 64);
    cvt_tail_k<<<1024, 256, 0, stream>>>(slab, 4096l * 64, 8, 64, xd, 8256, 8192);
    gemm2p_k<8256, 8256, 8256, 1><<<dim3(32, 16), 256, 0, stream>>>(xd, Wd_b, nullptr, hbuf, 2048, nullptr, 0);
  }

  rms_f32_k<<<4096, 256, 0, stream>>>(hbuf, lnf, tmpf);
  pool_k<<<dim3(8, 8), 256, 0, stream>>>(tmpf, amask, pooled);
  proj_k<<<1536, 256, 0, stream>>>(pooled, projW, projb, embraw);
  norm_k<<<8, 256, 0, stream>>>(embraw, (float*)d_out);
}

// Round 13
// 2222.801 us; speedup vs baseline: 1.0979x; 1.0371x over previous
//
#include <hip/hip_runtime.h>

typedef __attribute__((ext_vector_type(8))) short short8;
typedef __attribute__((ext_vector_type(4))) float f32x4;

#define AS1 __attribute__((address_space(1)))
#define AS3 __attribute__((address_space(3)))

__device__ __forceinline__ unsigned short f2bf(float f) {
  unsigned int u = __float_as_uint(f);
  u = (u + 0x7fffu + ((u >> 16) & 1u)) >> 16;   // RNE
  return (unsigned short)u;
}
__device__ __forceinline__ float bf2f(unsigned short b) {
  return __uint_as_float(((unsigned int)b) << 16);
}

// ---------------- embedding gather ----------------
__global__ __launch_bounds__(256) void embed_k(const int* __restrict__ ids,
                                               const float* __restrict__ emb,
                                               float* __restrict__ h) {
  const int tok = blockIdx.x;
  const int id = ids[tok];
  const float4* s = (const float4*)(emb + (size_t)id * 2048);
  float4* d = (float4*)(h + (size_t)tok * 2048);
  d[threadIdx.x * 2] = s[threadIdx.x * 2];
  d[threadIdx.x * 2 + 1] = s[threadIdx.x * 2 + 1];
}

// ---------------- rope tables ----------------
__global__ __launch_bounds__(256) void ropetab_k(float* __restrict__ ct, float* __restrict__ st) {
  int i = blockIdx.x * 256 + threadIdx.x;  // 32768
  int pos = i >> 6, j = i & 63;
  float inv = __expf(-(float)j * (1.0f / 64.0f) * logf(500000.0f));
  float ang = (float)pos * inv;
  ct[i] = cosf(ang);
  st[i] = sinf(ang);
}

// ---------------- weight conversion fp32 -> bf16 with LoRA-B augmentation ----------------
struct ConvSeg {
  const float* W; const float* Bm; unsigned short* out;
  int N, Kin, Kout, bcol0; long chunk0;
};
struct ConvDesc { long total; int nseg; ConvSeg seg[16]; };

__global__ __launch_bounds__(256) void conv_k(ConvDesc d, float bscale) {
  long c = (long)blockIdx.x * 256 + threadIdx.x;
  if (c >= d.total) return;
  int si = 0;
  while (si + 1 < d.nseg && c >= d.seg[si + 1].chunk0) ++si;
  const float* W = d.seg[si].W;
  const float* Bm = d.seg[si].Bm;
  unsigned short* out = d.seg[si].out;
  const int Kin = d.seg[si].Kin, Kout = d.seg[si].Kout, bcol0 = d.seg[si].bcol0;
  long lc = c - d.seg[si].chunk0;
  int cpr = Kout >> 3;
  int row = (int)(lc / cpr);
  int col0 = ((int)(lc - (long)row * cpr)) << 3;
  union { unsigned short u[8]; uint4 v; } o;
  if (col0 < Kin) {
    const float4* src = (const float4*)(W + (size_t)row * Kin + col0);
    float4 a = src[0], b = src[1];
    o.u[0]=f2bf(a.x); o.u[1]=f2bf(a.y); o.u[2]=f2bf(a.z); o.u[3]=f2bf(a.w);
    o.u[4]=f2bf(b.x); o.u[5]=f2bf(b.y); o.u[6]=f2bf(b.z); o.u[7]=f2bf(b.w);
  } else {
    #pragma unroll
    for (int j = 0; j < 8; ++j) {
      int bj = col0 + j - bcol0;
      float v = (Bm && bj >= 0 && bj < 64) ? Bm[(size_t)row * 64 + bj] * bscale : 0.0f;
      o.u[j] = f2bf(v);
    }
  }
  *(uint4*)(out + (size_t)row * Kout + col0) = o.v;
}

// ---------------- RMSNorm (D=2048) -> bf16 row at stride ldx ----------------
__global__ __launch_bounds__(256) void rms_bf16_k(const float* __restrict__ h,
                                                  const float* __restrict__ w,
                                                  unsigned short* __restrict__ out, int ldx) {
  const int tok = blockIdx.x, t = threadIdx.x;
  const float4* row = (const float4*)(h + (size_t)tok * 2048);
  float4 v0 = row[t * 2], v1 = row[t * 2 + 1];
  float ss = v0.x*v0.x+v0.y*v0.y+v0.z*v0.z+v0.w*v0.w
           + v1.x*v1.x+v1.y*v1.y+v1.z*v1.z+v1.w*v1.w;
  #pragma unroll
  for (int x = 32; x > 0; x >>= 1) ss += __shfl_xor(ss, x, 64);
  __shared__ float sred[4];
  if ((t & 63) == 0) sred[t >> 6] = ss;
  __syncthreads();
  ss = sred[0] + sred[1] + sred[2] + sred[3];
  const float sc = rsqrtf(ss * (1.0f / 2048.0f) + 1e-5f);
  const int d0 = t * 8;
  const float vals[8] = {v0.x, v0.y, v0.z, v0.w, v1.x, v1.y, v1.z, v1.w};
  union { unsigned short u[8]; uint4 v; } o;
  #pragma unroll
  for (int j = 0; j < 8; ++j) o.u[j] = f2bf(vals[j] * sc * w[d0 + j]);
  *(uint4*)(out + (size_t)tok * ldx + d0) = o.v;
}

// ---------------- final RMSNorm -> fp32 ----------------
__global__ __launch_bounds__(256) void rms_f32_k(const float* __restrict__ h,
                                                 const float* __restrict__ w,
                                                 float* __restrict__ out) {
  const int tok = blockIdx.x, t = threadIdx.x;
  const float4* row = (const float4*)(h + (size_t)tok * 2048);
  float4 v0 = row[t * 2], v1 = row[t * 2 + 1];
  float ss = v0.x*v0.x+v0.y*v0.y+v0.z*v0.z+v0.w*v0.w
           + v1.x*v1.x+v1.y*v1.y+v1.z*v1.z+v1.w*v1.w;
  #pragma unroll
  for (int x = 32; x > 0; x >>= 1) ss += __shfl_xor(ss, x, 64);
  __shared__ float sred[4];
  if ((t & 63) == 0) sred[t >> 6] = ss;
  __syncthreads();
  ss = sred[0] + sred[1] + sred[2] + sred[3];
  const float sc = rsqrtf(ss * (1.0f / 2048.0f) + 1e-5f);
  const int d0 = t * 8;
  float4 o0, o1;
  o0.x = v0.x * sc * w[d0 + 0]; o0.y = v0.y * sc * w[d0 + 1];
  o0.z = v0.z * sc * w[d0 + 2]; o0.w = v0.w * sc * w[d0 + 3];
  o1.x = v1.x * sc * w[d0 + 4]; o1.y = v1.y * sc * w[d0 + 5];
  o1.z = v1.z * sc * w[d0 + 6]; o1.w = v1.w * sc * w[d0 + 7];
  float4* op = (float4*)(out + (size_t)tok * 2048 + d0);
  op[0] = o0; op[1] = o1;
}

// ---------------- split-K LoRA GEMM: f32 partial slabs (no atomics) ----------------
__global__ __launch_bounds__(256) void gemm_sk_k(
    const unsigned short* __restrict__ A, int lda,
    const unsigned short* __restrict__ B, int ldb, int Nb, int KS,
    float* __restrict__ Cf, long slabStride, int ldc) {
  __shared__ unsigned short As[128 * 64];
  __shared__ unsigned short Bs[128 * 64];
  const int t = threadIdx.x;
  const int w = t >> 6, l = t & 63;
  const int lr = l & 15, lg = l >> 4;
  const int m0 = blockIdx.x * 128;
  const int n0 = blockIdx.y * 128;
  const int wr = (w >> 1) * 64, wc = (w & 1) * 64;
  const int koff = blockIdx.z * KS;

  const f32x4 vzero = {0.f, 0.f, 0.f, 0.f};
  f32x4 acc[4][4];
  #pragma unroll
  for (int i = 0; i < 4; ++i)
    #pragma unroll
    for (int j = 0; j < 4; ++j) acc[i][j] = vzero;

  const int scol = ((t & 7) ^ ((t >> 3) & 7)) * 8;
  const unsigned short* aSrc = A + (size_t)(m0 + (t >> 3)) * lda + koff + scol;
  const int bRow0 = n0 + (t >> 3);

  for (int k0 = 0; k0 < KS; k0 += 64) {
    __syncthreads();
    #pragma unroll
    for (int i = 0; i < 4; ++i) {
      __builtin_amdgcn_global_load_lds((const AS1 void*)(aSrc + (size_t)i * 32 * lda + k0),
                                       (AS3 void*)(As + i * 2048 + w * 512), 16, 0, 0);
      int br = bRow0 + i * 32; br = br < Nb ? br : Nb - 1;
      __builtin_amdgcn_global_load_lds((const AS1 void*)(B + (size_t)br * ldb + koff + k0 + scol),
                                       (AS3 void*)(Bs + i * 2048 + w * 512), 16, 0, 0);
    }
    __syncthreads();
    #pragma unroll
    for (int kk = 0; kk < 64; kk += 32) {
      const int swz = ((lg + (kk >> 3)) ^ (lr & 7)) << 3;
      short8 af[4], bfr[4];
      #pragma unroll
      for (int i = 0; i < 4; ++i)
        af[i] = *(const short8*)&As[(wr + i * 16 + lr) * 64 + swz];
      #pragma unroll
      for (int j = 0; j < 4; ++j)
        bfr[j] = *(const short8*)&Bs[(wc + j * 16 + lr) * 64 + swz];
      #pragma unroll
      for (int i = 0; i < 4; ++i)
        #pragma unroll
        for (int j = 0; j < 4; ++j)
          acc[i][j] = __builtin_amdgcn_mfma_f32_16x16x32_bf16(af[i], bfr[j], acc[i][j], 0, 0, 0);
    }
  }

  float* slab = Cf + (size_t)blockIdx.z * slabStride;
  #pragma unroll
  for (int i = 0; i < 4; ++i) {
    const int row = m0 + wr + i * 16 + lg * 4;
    #pragma unroll
    for (int j = 0; j < 4; ++j) {
      const int col = n0 + wc + j * 16 + lr;
      if (col < Nb) {
        #pragma unroll
        for (int r = 0; r < 4; ++r)
          slab[(size_t)(row + r) * ldc + col] = acc[i][j][r];
      }
    }
  }
}

// ---------------- sum split-K slabs -> bf16 tail columns ----------------
__global__ __launch_bounds__(256) void cvt_tail_k(const float* __restrict__ slab,
                                                  long slabStride, int S, int N,
                                                  unsigned short* __restrict__ out,
                                                  int ldx, int col0) {
  int i = blockIdx.x * 256 + threadIdx.x;
  if (i >= 4096 * N) return;
  int row = i / N, col = i - row * N;
  float s = 0.f;
  for (int z = 0; z < S; ++z) s += slab[(size_t)z * slabStride + (size_t)row * N + col];
  out[(size_t)row * ldx + col0 + col] = f2bf(s);
}

// ---------------- big GEMM: 256x256, K-half ring, BARRIER-MINIMAL (2 barriers/K-tile) ----------------
// Hazard ledger: slot staged at tile tt was last read at tile tt-1 BEFORE the other half's
// pre-read barrier -> all post-MFMA / same-slot-re-read barriers are redundant. Per K-tile:
// P0{issue stA(x'), vmcnt(6), BARRIER, read s0(a0,b0), 16 MFMA}
// P1{issue stB(x'), read s0(a1), 16 MFMA}                       (no sync)
// P2{issue stA(y'), vmcnt(6), BARRIER, read s1(a0,b1), 16 MFMA}
// P3{issue stB(y'), read s1(a1), 16 MFMA}                       (no sync)
// vmcnt ledger (per wave): entry 8 outstanding; P0 issue->10, wait 6 (drains x, issued a
// full K-tile earlier); P2 issue->10, wait 6 (drains y); exit 8. Tail: 4 / 0.
// No explicit lgkmcnt (ds_read->MFMA deps compiler-visible). epi runtime.
__global__ __launch_bounds__(512, 2) void gemm8p_k(
    const unsigned short* __restrict__ A, int lda,
    const unsigned short* __restrict__ B, int ldb, int K,
    unsigned short* __restrict__ Cb, float* __restrict__ Cf, int ldc, int epi,
    const unsigned short* __restrict__ G, int ldg) {
  __shared__ __attribute__((aligned(16))) unsigned short As[4][256 * 32];
  __shared__ __attribute__((aligned(16))) unsigned short Bs[4][256 * 32];
  const int t = threadIdx.x;
  const int w = t >> 6, l = t & 63;
  const int lr = l & 15, lg = l >> 4;

  const int gy = gridDim.y;
  int flat = blockIdx.x + gridDim.x * blockIdx.y;
  const int cpx = (gridDim.x * gy) >> 3;
  flat = (flat & 7) * cpx + (flat >> 3);
  const int m0 = (flat / gy) * 256;
  const int n0 = (flat % gy) * 256;

  const int wr = (w >> 2) * 128;
  const int wc = (w & 3) * 64;

  const f32x4 vzero = {0.f, 0.f, 0.f, 0.f};
  f32x4 acc[8][4];
  #pragma unroll
  for (int i = 0; i < 8; ++i)
    #pragma unroll
    for (int j = 0; j < 4; ++j) acc[i][j] = vzero;

  const int x = (l & 7) ^ (l >> 3);
  const int srow = w * 32 + 2 * (l >> 3) + (x >> 2);
  const int scol = (x & 3) * 8;
  const unsigned short* aS0 = A + (size_t)(m0 + srow) * lda + scol;
  const unsigned short* aS1 = aS0 + (size_t)16 * lda;
  const unsigned short* bS0 = B + (size_t)(n0 + srow) * ldb + scol;
  const unsigned short* bS1 = bS0 + (size_t)16 * ldb;
  char* AsD = (char*)&As[0][0] + w * 2048;
  char* BsD = (char*)&Bs[0][0] + w * 2048;

  auto stA = [&](int slot, int kb) {
    __builtin_amdgcn_global_load_lds((const AS1 void*)(aS0 + kb),
                                     (AS3 void*)(AsD + slot * 16384), 16, 0, 0);
    __builtin_amdgcn_global_load_lds((const AS1 void*)(aS1 + kb),
                                     (AS3 void*)(AsD + slot * 16384 + 1024), 16, 0, 0);
  };
  auto stB = [&](int slot, int kb) {
    __builtin_amdgcn_global_load_lds((const AS1 void*)(bS0 + kb),
                                     (AS3 void*)(BsD + slot * 16384), 16, 0, 0);
    __builtin_amdgcn_global_load_lds((const AS1 void*)(bS1 + kb),
                                     (AS3 void*)(BsD + slot * 16384 + 1024), 16, 0, 0);
  };

  const int rdoff = (lr >> 1) * 128 + (((lg | ((lr & 1) << 2)) ^ (lr >> 1)) << 4);
  #define RD(arr, slot, Rb) \
    (*(const short8*)((const char*)(arr) + (slot) * 16384 + (Rb) * 64 + rdoff))

  // prologue: tile0 both halves in flight (8 outstanding) — matches loop entry invariant
  stA(0, 0); stB(0, 0);
  stA(1, 32); stB(1, 32);

  const int NT = K >> 6;
  short8 a0[4], a1[4], b0[4], b1[4];

  for (int tt = 0; tt < NT; ++tt) {
    const int g0 = 2 * tt;
    const int s0 = g0 & 3, s1 = (g0 + 1) & 3, vA = (g0 + 2) & 3, vB = (g0 + 3) & 3;
    const bool pf = (tt + 1 < NT);
    const int kbN = pf ? (tt + 1) * 64 : 0;

    // ---- P0: issue next-half0 A; drain x; barrier; K-half0 x C-rows wr.. ----
    if (pf) {
      stA(vA, kbN);
      asm volatile("s_waitcnt vmcnt(6)" ::: "memory");
    } else {
      asm volatile("s_waitcnt vmcnt(4)" ::: "memory");
    }
    __builtin_amdgcn_s_barrier();
    #pragma unroll
    for (int i = 0; i < 4; ++i) a0[i] = RD(As, s0, wr + i * 16);
    #pragma unroll
    for (int j = 0; j < 4; ++j) b0[j] = RD(Bs, s0, wc + j * 16);
    __builtin_amdgcn_s_setprio(1);
    #pragma unroll
    for (int i = 0; i < 4; ++i)
      #pragma unroll
      for (int j = 0; j < 4; ++j)
        acc[i][j] = __builtin_amdgcn_mfma_f32_16x16x32_bf16(a0[i], b0[j], acc[i][j], 0, 0, 0);
    __builtin_amdgcn_s_setprio(0);

    // ---- P1: issue next-half0 B; K-half0 x C-rows wr+64.. (same slot, no sync) ----
    if (pf) stB(vA, kbN);
    #pragma unroll
    for (int i = 0; i < 4; ++i) a1[i] = RD(As, s0, wr + 64 + i * 16);
    __builtin_amdgcn_s_setprio(1);
    #pragma unroll
    for (int i = 0; i < 4; ++i)
      #pragma unroll
      for (int j = 0; j < 4; ++j)
        acc[i + 4][j] = __builtin_amdgcn_mfma_f32_16x16x32_bf16(a1[i], b0[j], acc[i + 4][j], 0, 0, 0);
    __builtin_amdgcn_s_setprio(0);

    // ---- P2: issue next-half1 A; drain y; barrier; K-half1 x C-rows wr.. ----
    if (pf) {
      stA(vB, kbN + 32);
      asm volatile("s_waitcnt vmcnt(6)" ::: "memory");
    } else {
      asm volatile("s_waitcnt vmcnt(0)" ::: "memory");
    }
    __builtin_amdgcn_s_barrier();
    #pragma unroll
    for (int i = 0; i < 4; ++i) a0[i] = RD(As, s1, wr + i * 16);
    #pragma unroll
    for (int j = 0; j < 4; ++j) b1[j] = RD(Bs, s1, wc + j * 16);
    __builtin_amdgcn_s_setprio(1);
    #pragma unroll
    for (int i = 0; i < 4; ++i)
      #pragma unroll
      for (int j = 0; j < 4; ++j)
        acc[i][j] = __builtin_amdgcn_mfma_f32_16x16x32_bf16(a0[i], b1[j], acc[i][j], 0, 0, 0);
    __builtin_amdgcn_s_setprio(0);

    // ---- P3: issue next-half1 B; K-half1 x C-rows wr+64.. (same slot, no sync) ----
    if (pf) stB(vB, kbN + 32);
    #pragma unroll
    for (int i = 0; i < 4; ++i) a1[i] = RD(As, s1, wr + 64 + i * 16);
    __builtin_amdgcn_s_setprio(1);
    #pragma unroll
    for (int i = 0; i < 4; ++i)
      #pragma unroll
      for (int j = 0; j < 4; ++j)
        acc[i + 4][j] = __builtin_amdgcn_mfma_f32_16x16x32_bf16(a1[i], b1[j], acc[i + 4][j], 0, 0, 0);
    __builtin_amdgcn_s_setprio(0);
  }
  #undef RD

  #pragma unroll
  for (int i = 0; i < 8; ++i) {
    const int row = m0 + wr + i * 16 + lg * 4;
    #pragma unroll
    for (int j = 0; j < 4; ++j) {
      const int col = n0 + wc + j * 16 + lr;
      #pragma unroll
      for (int r = 0; r < 4; ++r) {
        float v = acc[i][j][r];
        size_t off = (size_t)(row + r) * ldc + col;
        if (epi == 0) {
          Cb[off] = f2bf(v);
        } else if (epi == 1) {
          Cf[off] += v;
        } else {
          float g = bf2f(G[(size_t)(row + r) * ldg + col]);
          Cb[off] = f2bf(g / (1.0f + __expf(-g)) * v);
        }
      }
    }
  }
}

// ---------------- 2p GEMM (small-N shapes, 512-block grids): 128x128, dbuf, swizzle ----------------
template<int K_, int LDA_, int LDB_, int EPI_>
__global__ __launch_bounds__(256) void gemm2p_k(
    const unsigned short* __restrict__ A,
    const unsigned short* __restrict__ B,
    unsigned short* __restrict__ Cb, float* __restrict__ Cf, int ldc,
    const unsigned short* __restrict__ G, int ldg) {
  __shared__ unsigned short As[2][128 * 64];
  __shared__ unsigned short Bs[2][128 * 64];
  const int t = threadIdx.x;
  const int w = t >> 6, l = t & 63;
  const int lr = l & 15, lg = l >> 4;

  const int gx = gridDim.x;
  int flat = blockIdx.x + gx * blockIdx.y;
  const int cpx = (gx * gridDim.y) >> 3;
  flat = (flat & 7) * cpx + (flat >> 3);
  const int m0 = (flat % gx) * 128;
  const int n0 = (flat / gx) * 128;

  const int wr = (w >> 1) * 64, wc = (w & 1) * 64;

  const f32x4 vzero = {0.f, 0.f, 0.f, 0.f};
  f32x4 acc[4][4];
  #pragma unroll
  for (int i = 0; i < 4; ++i)
    #pragma unroll
    for (int j = 0; j < 4; ++j) acc[i][j] = vzero;

  const int scol = ((t & 7) ^ ((t >> 3) & 7)) * 8;
  const unsigned short* aSrc = A + (size_t)(m0 + (t >> 3)) * LDA_ + scol;
  const unsigned short* bSrc = B + (size_t)(n0 + (t >> 3)) * LDB_ + scol;

  auto stage = [&](int buf, int k0) {
    #pragma unroll
    for (int i = 0; i < 4; ++i) {
      __builtin_amdgcn_global_load_lds((const AS1 void*)(aSrc + (size_t)i * 32 * LDA_ + k0),
                                       (AS3 void*)(&As[buf][i * 2048 + w * 512]), 16, 0, 0);
      __builtin_amdgcn_global_load_lds((const AS1 void*)(bSrc + (size_t)i * 32 * LDB_ + k0),
                                       (AS3 void*)(&Bs[buf][i * 2048 + w * 512]), 16, 0, 0);
    }
  };

  constexpr int NT = K_ / 64;
  stage(0, 0);
  __syncthreads();

  int cur = 0;
  for (int kt = 0; kt < NT; ++kt) {
    if (kt + 1 < NT) stage(cur ^ 1, (kt + 1) * 64);
    #pragma unroll
    for (int kk = 0; kk < 64; kk += 32) {
      const int swz = ((lg + (kk >> 3)) ^ (lr & 7)) << 3;
      short8 af[4], bfr[4];
      #pragma unroll
      for (int i = 0; i < 4; ++i)
        af[i] = *(const short8*)&As[cur][(wr + i * 16 + lr) * 64 + swz];
      #pragma unroll
      for (int j = 0; j < 4; ++j)
        bfr[j] = *(const short8*)&Bs[cur][(wc + j * 16 + lr) * 64 + swz];
      #pragma unroll
      for (int i = 0; i < 4; ++i)
        #pragma unroll
        for (int j = 0; j < 4; ++j)
          acc[i][j] = __builtin_amdgcn_mfma_f32_16x16x32_bf16(af[i], bfr[j], acc[i][j], 0, 0, 0);
    }
    __syncthreads();
    cur ^= 1;
  }

  #pragma unroll
  for (int i = 0; i < 4; ++i) {
    const int row = m0 + wr + i * 16 + lg * 4;
    #pragma unroll
    for (int j = 0; j < 4; ++j) {
      const int col = n0 + wc + j * 16 + lr;
      #pragma unroll
      for (int r = 0; r < 4; ++r) {
        float v = acc[i][j][r];
        size_t off = (size_t)(row + r) * ldc + col;
        if constexpr (EPI_ == 0) {
          Cb[off] = f2bf(v);
        } else if constexpr (EPI_ == 1) {
          Cf[off] += v;
        } else {
          float g = bf2f(G[(size_t)(row + r) * ldg + col]);
          Cb[off] = f2bf(g / (1.0f + __expf(-g)) * v);
        }
      }
    }
  }
}

// ---------------- RoPE in-place on qkv buffer ----------------
__global__ __launch_bounds__(256) void rope_k(unsigned short* __restrict__ qkv,
                                              const float* __restrict__ ct,
                                              const float* __restrict__ st) {
  const int tok = blockIdx.x;
  const int pid = blockIdx.y * 256 + threadIdx.x;  // 0..1535
  const int head = pid >> 6, j = pid & 63;
  const int s = tok & 511;
  unsigned short* base = qkv + (size_t)tok * 4096 + (head < 16 ? head * 128 : 2048 + (head - 16) * 128);
  const float c = ct[s * 64 + j], sn = st[s * 64 + j];
  const float x1 = bf2f(base[j]), x2 = bf2f(base[j + 64]);
  base[j] = f2bf(x1 * c - x2 * sn);
  base[j + 64] = f2bf(x2 * c + x1 * sn);
}

// ---------------- flash attention (K direct from global/L2; V transposed via LDS) ----------------
__global__ __launch_bounds__(256) void attn_k(const unsigned short* __restrict__ qkv,
                                              const int* __restrict__ amask,
                                              unsigned short* __restrict__ xo) {
  const int q0 = blockIdx.x * 64;
  const int hh = blockIdx.y;
  const int b = blockIdx.z;
  const int kvh = hh >> 1;
  const int t = threadIdx.x, w = t >> 6, l = t & 63;
  const int lr = l & 15, lg = l >> 4;

  const size_t rowbase = (size_t)b * 512 * 4096;
  const unsigned short* Q = qkv + rowbase + hh * 128;
  const unsigned short* Kp = qkv + rowbase + 2048 + kvh * 128;
  const unsigned short* Vp = qkv + rowbase + 3072 + kvh * 128;

  __shared__ unsigned short Vt[128 * 32];
  __shared__ unsigned short Ps[4][16 * 32];

  short8 qf[4];
  const unsigned short* qrow = Q + (size_t)(q0 + w * 16 + lr) * 4096;
  #pragma unroll
  for (int kk = 0; kk < 4; ++kk) qf[kk] = *(const short8*)(qrow + kk * 32 + lg * 8);

  const f32x4 vzero = {0.f, 0.f, 0.f, 0.f};
  f32x4 accO[8];
  #pragma unroll
  for (int i = 0; i < 8; ++i) accO[i] = vzero;
  float mrow[4], lrow[4];
  #pragma unroll
  for (int r = 0; r < 4; ++r) { mrow[r] = -1e30f; lrow[r] = 0.f; }

  const int qpos0 = q0 + w * 16 + lg * 4;
  const int ktiles = (q0 + 64) >> 5;
  for (int kt = 0; kt < ktiles; ++kt) {
    const int kbase = kt * 32;

    f32x4 sf[2]; sf[0] = vzero; sf[1] = vzero;
    #pragma unroll
    for (int nt = 0; nt < 2; ++nt)
      #pragma unroll
      for (int kk = 0; kk < 4; ++kk) {
        short8 kf = *(const short8*)(Kp + (size_t)(kbase + nt * 16 + lr) * 4096 + kk * 32 + lg * 8);
        sf[nt] = __builtin_amdgcn_mfma_f32_16x16x32_bf16(qf[kk], kf, sf[nt], 0, 0, 0);
      }

    float pv[2][4], pmax[4];
    #pragma unroll
    for (int r = 0; r < 4; ++r) pmax[r] = -1e30f;
    #pragma unroll
    for (int nt = 0; nt < 2; ++nt) {
      const int key = kbase + nt * 16 + lr;
      const bool okm = amask[b * 512 + key] != 0;
      #pragma unroll
      for (int r = 0; r < 4; ++r) {
        float s = sf[nt][r] * 0.08838834764831845f;
        if (!okm || key > qpos0 + r) s = -1e9f;
        pv[nt][r] = s;
        pmax[r] = fmaxf(pmax[r], s);
      }
    }
    #pragma unroll
    for (int x = 1; x < 16; x <<= 1)
      #pragma unroll
      for (int r = 0; r < 4; ++r) pmax[r] = fmaxf(pmax[r], __shfl_xor(pmax[r], x, 64));

    float alpha[4];
    #pragma unroll
    for (int r = 0; r < 4; ++r) {
      float mn = fmaxf(mrow[r], pmax[r]);
      alpha[r] = __expf(mrow[r] - mn);
      mrow[r] = mn;
    }
    float rowsum[4];
    #pragma unroll
    for (int r = 0; r < 4; ++r) {
      float p0 = __expf(pv[0][r] - mrow[r]);
      float p1 = __expf(pv[1][r] - mrow[r]);
      pv[0][r] = p0; pv[1][r] = p1;
      rowsum[r] = p0 + p1;
    }
    #pragma unroll
    for (int x = 1; x < 16; x <<= 1)
      #pragma unroll
      for (int r = 0; r < 4; ++r) rowsum[r] += __shfl_xor(rowsum[r], x, 64);
    #pragma unroll
    for (int r = 0; r < 4; ++r) lrow[r] = lrow[r] * alpha[r] + rowsum[r];
    #pragma unroll
    for (int nt = 0; nt < 8; ++nt)
      #pragma unroll
      for (int r = 0; r < 4; ++r) accO[nt][r] *= alpha[r];

    __syncthreads();

    #pragma unroll
    for (int c = 0; c < 2; ++c) {
      int chunk = c * 256 + t;
      int key = chunk >> 4, ch = chunk & 15;
      short8 v = *(const short8*)(Vp + (size_t)(kbase + key) * 4096 + ch * 8);
      #pragma unroll
      for (int j = 0; j < 8; ++j) Vt[(ch * 8 + j) * 32 + key] = ((const unsigned short*)&v)[j];
    }
    #pragma unroll
    for (int nt = 0; nt < 2; ++nt)
      #pragma unroll
      for (int r = 0; r < 4; ++r)
        Ps[w][(lg * 4 + r) * 32 + nt * 16 + lr] = f2bf(pv[nt][r]);
    __syncthreads();

    short8 pa = *(const short8*)&Ps[w][lr * 32 + lg * 8];
    #pragma unroll
    for (int nt = 0; nt < 8; ++nt) {
      short8 vb = *(const short8*)&Vt[(nt * 16 + lr) * 32 + lg * 8];
      accO[nt] = __builtin_amdgcn_mfma_f32_16x16x32_bf16(pa, vb, accO[nt], 0, 0, 0);
    }
  }

  const size_t tokbase = ((size_t)b * 512 + qpos0) * 2112;
  #pragma unroll
  for (int nt = 0; nt < 8; ++nt) {
    const int col = hh * 128 + nt * 16 + lr;
    #pragma unroll
    for (int r = 0; r < 4; ++r)
      xo[tokbase + (size_t)r * 2112 + col] = f2bf(accO[nt][r] / lrow[r]);
  }
}

// ---------------- masked mean pool ----------------
__global__ __launch_bounds__(256) void pool_k(const float* __restrict__ tmpf,
                                              const int* __restrict__ amask,
                                              float* __restrict__ pooled) {
  const int b = blockIdx.y;
  const int d = blockIdx.x * 256 + threadIdx.x;
  float acc = 0.f, ms = 0.f;
  for (int s = 0; s < 512; ++s) {
    float m = (float)amask[b * 512 + s];
    acc += tmpf[((size_t)b * 512 + s) * 2048 + d] * m;
    ms += m;
  }
  pooled[b * 2048 + d] = acc / fmaxf(ms, 1e-9f);
}

// ---------------- projection ----------------
__global__ __launch_bounds__(256) void proj_k(const float* __restrict__ pooled,
                                              const float* __restrict__ W,
                                              const float* __restrict__ bias,
                                              float* __restrict__ emb) {
  const int idx = blockIdx.x * 4 + (threadIdx.x >> 6);
  const int l = threadIdx.x & 63;
  const int b = idx / 768, pcol = idx - b * 768;
  const float* x = pooled + b * 2048;
  const float* wr = W + (size_t)pcol * 2048;
  float acc = 0.f;
  #pragma unroll
  for (int i = 0; i < 32; ++i) acc += x[l + i * 64] * wr[l + i * 64];
  #pragma unroll
  for (int xm = 32; xm > 0; xm >>= 1) acc += __shfl_xor(acc, xm, 64);
  if (l == 0) emb[b * 768 + pcol] = acc + bias[pcol];
}

// ---------------- L2 normalize ----------------
__global__ __launch_bounds__(256) void norm_k(const float* __restrict__ emb, float* __restrict__ out) {
  const int b = blockIdx.x, t = threadIdx.x;
  float v[3]; float ss = 0.f;
  #pragma unroll
  for (int i = 0; i < 3; ++i) { v[i] = emb[b * 768 + t + i * 256]; ss += v[i] * v[i]; }
  #pragma unroll
  for (int x = 32; x > 0; x >>= 1) ss += __shfl_xor(ss, x, 64);
  __shared__ float sred[4];
  if ((t & 63) == 0) sred[t >> 6] = ss;
  __syncthreads();
  ss = sred[0] + sred[1] + sred[2] + sred[3];
  const float inv = 1.0f / fmaxf(sqrtf(ss), 1e-12f);
  #pragma unroll
  for (int i = 0; i < 3; ++i) out[b * 768 + t + i * 256] = v[i] * inv;
}

extern "C" void kernel_launch(void* const* d_in, const int* in_sizes, int n_in,
                              void* d_out, int out_size, void* d_ws, size_t ws_size,
                              hipStream_t stream) {
  const int* ids = (const int*)d_in[0];
  const int* amask = (const int*)d_in[1];
  const float* tok_emb = (const float*)d_in[2];
  const float* Wq = (const float*)d_in[3];
  const float* Wk = (const float*)d_in[4];
  const float* Wv = (const float*)d_in[5];
  const float* Wo = (const float*)d_in[6];
  const float* Wg = (const float*)d_in[7];
  const float* Wu = (const float*)d_in[8];
  const float* Wd = (const float*)d_in[9];
  const float* Aq = (const float*)d_in[10];
  const float* Bq = (const float*)d_in[11];
  const float* Ak = (const float*)d_in[12];
  const float* Bk = (const float*)d_in[13];
  const float* Av = (const float*)d_in[14];
  const float* Bv = (const float*)d_in[15];
  const float* Ao = (const float*)d_in[16];
  const float* Bo = (const float*)d_in[17];
  const float* Ag = (const float*)d_in[18];
  const float* Bg = (const float*)d_in[19];
  const float* Au = (const float*)d_in[20];
  const float* Bu = (const float*)d_in[21];
  const float* Ad = (const float*)d_in[22];
  const float* Bd = (const float*)d_in[23];
  const float* ln1 = (const float*)d_in[24];
  const float* ln2 = (const float*)d_in[25];
  const float* lnf = (const float*)d_in[26];
  const float* projW = (const float*)d_in[27];
  const float* projb = (const float*)d_in[28];

  typedef unsigned short u16;
  char* p = (char*)d_ws;
  auto take = [&](size_t n) { char* r = p; p += (n + 255) & ~(size_t)255; return r; };
  u16* Wqkv_b = (u16*)take(4096ull * 2240 * 2);
  u16* Wo_b   = (u16*)take(2048ull * 2112 * 2);
  u16* Wg_b   = (u16*)take(8192ull * 2112 * 2);
  u16* Wu_b   = (u16*)take(8192ull * 2176 * 2);
  u16* Wd_b   = (u16*)take(2048ull * 8256 * 2);
  u16* Aqkv_b = (u16*)take(192ull * 2048 * 2);
  u16* Agu_b  = (u16*)take(128ull * 2048 * 2);
  u16* Ao_b   = (u16*)take(64ull * 2048 * 2);
  u16* Ad_b   = (u16*)take(64ull * 8192 * 2);
  float* hbuf = (float*)take(4096ull * 2048 * 4);
  u16* xq     = (u16*)take(4096ull * 2240 * 2);
  u16* xo     = (u16*)take(4096ull * 2112 * 2);
  u16* xd     = (u16*)take(4096ull * 8256 * 2);
  u16* qkvb   = (u16*)take(4096ull * 4096 * 2);
  u16* gbuf   = (u16*)take(4096ull * 8192 * 2);
  float* ct   = (float*)take(512ull * 64 * 4);
  float* st   = (float*)take(512ull * 64 * 4);
  float* pooled = (float*)take(8ull * 2048 * 4);
  float* embraw = (float*)take(8ull * 768 * 4);
  float* tmpf = (float*)gbuf;
  float* slab = (float*)gbuf;   // split-K partials; stream-ordered reuse of gbuf
  (void)ws_size; (void)in_sizes; (void)n_in; (void)out_size;

  embed_k<<<4096, 256, 0, stream>>>(ids, tok_emb, hbuf);
  ropetab_k<<<128, 256, 0, stream>>>(ct, st);

  for (int l = 0; l < 2; ++l) {
    ConvDesc cd;
    long ch = 0; int si = 0;
    auto seg = [&](const float* W, const float* Bm, u16* out, int N, int Kin, int Kout, int bcol0) {
      cd.seg[si].W = W; cd.seg[si].Bm = Bm; cd.seg[si].out = out;
      cd.seg[si].N = N; cd.seg[si].Kin = Kin; cd.seg[si].Kout = Kout;
      cd.seg[si].bcol0 = bcol0; cd.seg[si].chunk0 = ch;
      ch += (long)N * (Kout >> 3); ++si;
    };
    seg(Wq + (size_t)l * 2048 * 2048, Bq + (size_t)l * 2048 * 64, Wqkv_b,               2048, 2048, 2240, 2048);
    seg(Wk + (size_t)l * 1024 * 2048, Bk + (size_t)l * 1024 * 64, Wqkv_b + 2048ull * 2240, 1024, 2048, 2240, 2112);
    seg(Wv + (size_t)l * 1024 * 2048, Bv + (size_t)l * 1024 * 64, Wqkv_b + 3072ull * 2240, 1024, 2048, 2240, 2176);
    seg(Wo + (size_t)l * 2048 * 2048, Bo + (size_t)l * 2048 * 64, Wo_b, 2048, 2048, 2112, 2048);
    seg(Wg + (size_t)l * 8192 * 2048, Bg + (size_t)l * 8192 * 64, Wg_b, 8192, 2048, 2112, 2048);
    seg(Wu + (size_t)l * 8192 * 2048, Bu + (size_t)l * 8192 * 64, Wu_b, 8192, 2048, 2176, 2112);
    seg(Wd + (size_t)l * 2048 * 8192, Bd + (size_t)l * 2048 * 64, Wd_b, 2048, 8192, 8256, 8192);
    seg(Aq + (size_t)l * 64 * 2048, nullptr, Aqkv_b,                64, 2048, 2048, 1 << 30);
    seg(Ak + (size_t)l * 64 * 2048, nullptr, Aqkv_b + 64ull * 2048, 64, 2048, 2048, 1 << 30);
    seg(Av + (size_t)l * 64 * 2048, nullptr, Aqkv_b + 128ull * 2048, 64, 2048, 2048, 1 << 30);
    seg(Ag + (size_t)l * 64 * 2048, nullptr, Agu_b,                 64, 2048, 2048, 1 << 30);
    seg(Au + (size_t)l * 64 * 2048, nullptr, Agu_b + 64ull * 2048,  64, 2048, 2048, 1 << 30);
    seg(Ao + (size_t)l * 64 * 2048, nullptr, Ao_b, 64, 2048, 2048, 1 << 30);
    seg(Ad + (size_t)l * 64 * 8192, nullptr, Ad_b, 64, 8192, 8192, 1 << 30);
    cd.nseg = si; cd.total = ch;
    conv_k<<<(int)((ch + 255) / 256), 256, 0, stream>>>(cd, 2.0f);

    // x = rms(h, ln1); t = x@[Aq;Ak;Av].T (split-K) ; qkv = [x|t] @ Wqkv'^T
    rms_bf16_k<<<4096, 256, 0, stream>>>(hbuf, ln1 + l * 2048, xq, 2240);
    gemm_sk_k<<<dim3(32, 2, 4), 256, 0, stream>>>(xq, 2240, Aqkv_b, 2048, 192, 512, slab, 4096l * 192, 192);
    cvt_tail_k<<<3072, 256, 0, stream>>>(slab, 4096l * 192, 4, 192, xq, 2240, 2048);
    gemm8p_k<<<dim3(16, 16), 512, 0, stream>>>(xq, 2240, Wqkv_b, 2240, 2240, qkvb, nullptr, 4096, 0, nullptr, 0);
    rope_k<<<dim3(4096, 6), 256, 0, stream>>>(qkvb, ct, st);
    attn_k<<<dim3(8, 16, 8), 256, 0, stream>>>(qkvb, amask, xo);
    // h += [o|t_o] @ Wo'^T  (small-N -> 2p, 512-block grid)
    gemm_sk_k<<<dim3(32, 1, 4), 256, 0, stream>>>(xo, 2112, Ao_b, 2048, 64, 512, slab, 4096l * 64, 64);
    cvt_tail_k<<<1024, 256, 0, stream>>>(slab, 4096l * 64, 4, 64, xo, 2112, 2048);
    gemm2p_k<2112, 2112, 2112, 1><<<dim3(32, 16), 256, 0, stream>>>(xo, Wo_b, nullptr, hbuf, 2048, nullptr, 0);
    // MLP: gate/up on 8p (512-block grids), down on 2p (512-block grid)
    rms_bf16_k<<<4096, 256, 0, stream>>>(hbuf, ln2 + l * 2048, xq, 2176);
    gemm_sk_k<<<dim3(32, 1, 4), 256, 0, stream>>>(xq, 2176, Agu_b, 2048, 128, 512, slab, 4096l * 128, 128);
    cvt_tail_k<<<2048, 256, 0, stream>>>(slab, 4096l * 128, 4, 128, xq, 2176, 2048);
    gemm8p_k<<<dim3(16, 32), 512, 0, stream>>>(xq, 2176, Wg_b, 2112, 2112, gbuf, nullptr, 8192, 0, nullptr, 0);
    gemm8p_k<<<dim3(16, 32), 512, 0, stream>>>(xq, 2176, Wu_b, 2176, 2176, xd, nullptr, 8256, 2, gbuf, 8192);
    gemm_sk_k<<<dim3(32, 1, 8), 256, 0, stream>>>(xd, 8256, Ad_b, 8192, 64, 1024, slab, 4096l * 64, 64);
    cvt_tail_k<<<1024, 256, 0, stream>>>(slab, 4096l * 64, 8, 64, xd, 8256, 8192);
    gemm2p_k<8256, 8256, 8256, 1><<<dim3(32, 16), 256, 0, stream>>>(xd, Wd_b, nullptr, hbuf, 2048, nullptr, 0);
  }

  rms_f32_k<<<4096, 256, 0, stream>>>(hbuf, lnf, tmpf);
  pool_k<<<dim3(8, 8), 256, 0, stream>>>(tmpf, amask, pooled);
  proj_k<<<1536, 256, 0, stream>>>(pooled, projW, projb, embraw);
  norm_k<<<8, 256, 0, stream>>>(embraw, (float*)d_out);
}